// Round 11
// baseline (1322.809 us; speedup 1.0000x reference)
//
#include <hip/hip_runtime.h>

#define H 128
typedef unsigned short u16;
typedef __attribute__((ext_vector_type(8))) short bf16x8;
typedef __attribute__((ext_vector_type(4))) float f32x4;

// ---------------------------------------------------------------- utilities

static inline int gridFor(long long work, int block, int cap = 16384){
  long long g = (work + block - 1) / block;
  if (g > cap) g = cap;
  if (g < 1) g = 1;
  return (int)g;
}

__device__ __forceinline__ float waveReduceSum(float v){
  #pragma unroll
  for(int off = 32; off > 0; off >>= 1) v += __shfl_down(v, off);
  return v;
}

__device__ __forceinline__ float bflo(unsigned v){ return __uint_as_float(v << 16); }
__device__ __forceinline__ float bfhi(unsigned v){ return __uint_as_float(v & 0xffff0000u); }
__device__ __forceinline__ u16 f2bf(float f){
  unsigned u = __float_as_uint(f);
  return (u16)((u + 0x7fffu + ((u >> 16) & 1u)) >> 16);
}
__device__ __forceinline__ unsigned pack2(float lo, float hi){
  return (unsigned)f2bf(lo) | ((unsigned)f2bf(hi) << 16);
}

// ---------------------------------------------------------------- bucketed CSR build
#define BSHIFT 9
#define CH 2048

template<bool HAS_ATTR>
__global__ __launch_bounds__(256) void part_kernel(
    const int* __restrict__ src, const int* __restrict__ dst,
    const float* __restrict__ attr, int* __restrict__ bcur,
    int2* __restrict__ bpairs, float* __restrict__ battr, int E, int cap){
  __shared__ int hist[256];
  __shared__ int hscan[256];
  __shared__ int hbase[256];
  __shared__ int hcur[256];
  __shared__ int2 buf[CH];
  __shared__ float abuf[HAS_ATTR ? CH : 1];

  const int t = threadIdx.x;
  const int e0 = blockIdx.x * CH;
  const int cnt = min(CH, E - e0);

  hist[t] = 0; hcur[t] = 0;
  __syncthreads();

  #pragma unroll
  for(int j = 0; j < 8; j++){
    int i = e0 + j*256 + t;
    if(i - e0 < cnt) atomicAdd(&hist[dst[i] >> BSHIFT], 1);
  }
  __syncthreads();

  {
    int v = hist[t];
    int lane = t & 63, wid = t >> 6;
    int incl = v;
    #pragma unroll
    for(int off = 1; off < 64; off <<= 1){
      int u = __shfl_up(incl, off);
      if(lane >= off) incl += u;
    }
    __shared__ int ws4[4];
    if(lane == 63) ws4[wid] = incl;
    __syncthreads();
    int wofs = 0;
    for(int wj = 0; wj < wid; wj++) wofs += ws4[wj];
    hscan[t] = wofs + incl - v;
    hbase[t] = (v > 0) ? atomicAdd(&bcur[t], v) : 0;
  }
  __syncthreads();

  #pragma unroll
  for(int j = 0; j < 8; j++){
    int i = e0 + j*256 + t;
    if(i - e0 < cnt){
      int d = dst[i], s = src[i];
      int b = d >> BSHIFT;
      int lp = atomicAdd(&hcur[b], 1);
      int slot = hscan[b] + lp;
      buf[slot] = make_int2(d, s);
      if(HAS_ATTR) abuf[slot] = attr[i];
    }
  }
  __syncthreads();

  for(int u = t; u < cnt; u += 256){
    int2 pr = buf[u];
    int b = pr.x >> BSHIFT;
    int g = b * cap + hbase[b] + (u - hscan[b]);
    bpairs[g] = pr;
    if(HAS_ATTR) battr[g] = abuf[u];
  }
}

__global__ void bucket_scan(const int* __restrict__ bcur, int* __restrict__ bbase,
                            int* __restrict__ rp0, int* __restrict__ rp1,
                            int* __restrict__ rp2, int* __restrict__ rp3,
                            int n0, int n1, int n2, int n3){
  int g = blockIdx.x;
  int n = (g == 0) ? n0 : (g == 1) ? n1 : (g == 2) ? n2 : n3;
  int* rowp = (g == 0) ? rp0 : (g == 1) ? rp1 : (g == 2) ? rp2 : rp3;
  int NB = (n + 511) >> BSHIFT;
  int t = threadIdx.x;
  int v = (t < NB) ? bcur[g*256 + t] : 0;
  int lane = t & 63, wid = t >> 6;
  int incl = v;
  #pragma unroll
  for(int off = 1; off < 64; off <<= 1){
    int u = __shfl_up(incl, off);
    if(lane >= off) incl += u;
  }
  __shared__ int ws4[4];
  if(lane == 63) ws4[wid] = incl;
  __syncthreads();
  int wofs = 0;
  for(int wj = 0; wj < wid; wj++) wofs += ws4[wj];
  bbase[g*256 + t] = wofs + incl - v;
  if(t == 0) rowp[n] = ws4[0] + ws4[1] + ws4[2] + ws4[3];
}

template<bool HAS_ATTR, bool DINV>
__global__ __launch_bounds__(256) void build_kernel(
    const int2* __restrict__ bpairs, const float* __restrict__ battr,
    const int* __restrict__ bcur, const int* __restrict__ bbase,
    int* __restrict__ rowp, int* __restrict__ col, float* __restrict__ attrp,
    float* __restrict__ dinv, int cap, int n){
  __shared__ int hist[512];
  __shared__ int hcur[512];
  __shared__ int ws4[4];

  const int b = blockIdx.x;
  const int t = threadIdx.x;
  const int d0 = b << BSHIFT;
  const int dn = min(512, n - d0);
  const int cnt = bcur[b];
  const int base = bbase[b];
  const int2* ep = bpairs + (size_t)b * cap;

  hist[t] = 0; hist[t + 256] = 0;
  __syncthreads();
  for(int u = t; u < cnt; u += 256) atomicAdd(&hist[ep[u].x - d0], 1);
  __syncthreads();

  int a0 = hist[2*t], a1 = hist[2*t + 1];
  int s = a0 + a1;
  int lane = t & 63, wid = t >> 6;
  int incl = s;
  #pragma unroll
  for(int off = 1; off < 64; off <<= 1){
    int u = __shfl_up(incl, off);
    if(lane >= off) incl += u;
  }
  if(lane == 63) ws4[wid] = incl;
  __syncthreads();
  int wofs = 0;
  for(int wj = 0; wj < wid; wj++) wofs += ws4[wj];
  int excl = wofs + incl - s;
  __syncthreads();
  hcur[2*t] = excl; hcur[2*t + 1] = excl + a0;
  if(2*t < dn){
    rowp[d0 + 2*t] = base + excl;
    if(DINV) dinv[d0 + 2*t] = a0 > 0 ? rsqrtf((float)a0) : 0.f;
  }
  if(2*t + 1 < dn){
    rowp[d0 + 2*t + 1] = base + excl + a0;
    if(DINV) dinv[d0 + 2*t + 1] = a1 > 0 ? rsqrtf((float)a1) : 0.f;
  }
  __syncthreads();

  for(int u = t; u < cnt; u += 256){
    int2 pr = ep[u];
    int pos = base + atomicAdd(&hcur[pr.x - d0], 1);
    col[pos] = pr.y;
    if(HAS_ATTR) attrp[pos] = battr[(size_t)b * cap + u];
  }
}

// ---------------------------------------------------------------- weights to bf16 frag-major

__global__ void cvt_weights(const float* __restrict__ Wl, const float* __restrict__ Wr,
                            const float* __restrict__ Wsrc, u16* __restrict__ Wb){
  const int total = 15 * H * H;
  for(int t = blockIdx.x*blockDim.x + threadIdx.x; t < total; t += gridDim.x*blockDim.x){
    int mat = t >> 14, idx = t & 16383;
    int k = idx >> 7, colj = idx & 127;
    const float* srcp = (mat < 7) ? (Wl + ((size_t)mat << 14))
                       : (mat < 14) ? (Wr + ((size_t)(mat - 7) << 14))
                       : Wsrc;
    Wb[((size_t)mat << 14) + (size_t)colj*H + k] = f2bf(srcp[idx]);
  }
}

__global__ void mat_vec_row(const float* __restrict__ W, const float* __restrict__ a,
                            float* __restrict__ outv){
  int k = threadIdx.x;
  if(k < H){
    float s = 0.f;
    for(int j = 0; j < H; j++) s += W[(size_t)k*H + j] * a[j];
    outv[k] = s;
  }
}

__global__ void dot128(const float* __restrict__ a, const float* __restrict__ b,
                       float* __restrict__ o){
  int l = threadIdx.x;
  float acc = a[l]*b[l] + a[l+64]*b[l+64];
  acc = waveReduceSum(acc);
  if(l == 0) o[0] = acc;
}

// ---------------------------------------------------------------- TAG (padded 8-float rows, dinv in slot 7)

template<int C>
__global__ void pack_rows(const float* __restrict__ x, const float* __restrict__ dinv,
                          float* __restrict__ xp, int N){
  for(int i = blockIdx.x*blockDim.x + threadIdx.x; i < N; i += gridDim.x*blockDim.x){
    #pragma unroll
    for(int k = 0; k < C; k++) xp[(size_t)i*8 + k] = x[(size_t)i*C + k];
    xp[(size_t)i*8 + 7] = dinv[i];
  }
}

template<int C>
__global__ void csr_tag_hop8(const int* __restrict__ rowp, const int* __restrict__ col,
                             const float* __restrict__ hin, float* __restrict__ hout, int N){
  for(int i = blockIdx.x*blockDim.x + threadIdx.x; i < N; i += gridDim.x*blockDim.x){
    int b = rowp[i], e = rowp[i+1];
    float dd = hin[(size_t)i*8 + 7];
    float acc0[C], acc1[C];
    #pragma unroll
    for(int k = 0; k < C; k++){ acc0[k] = 0.f; acc1[k] = 0.f; }
    int p = b;
    for(; p + 2 <= e; p += 2){
      const float* r0 = &hin[(size_t)col[p]   * 8];
      const float* r1 = &hin[(size_t)col[p+1] * 8];
      float w0 = r0[7] * dd, w1 = r1[7] * dd;
      #pragma unroll
      for(int k = 0; k < C; k++){
        acc0[k] += r0[k] * w0;
        acc1[k] += r1[k] * w1;
      }
    }
    if(p < e){
      const float* r0 = &hin[(size_t)col[p] * 8];
      float w0 = r0[7] * dd;
      #pragma unroll
      for(int k = 0; k < C; k++) acc0[k] += r0[k] * w0;
    }
    #pragma unroll
    for(int k = 0; k < C; k++) hout[(size_t)i*8 + k] = acc0[k] + acc1[k];
    hout[(size_t)i*8 + 7] = dd;
  }
}

template<int C>
__global__ __launch_bounds__(256) void tag_fuse(
    const float* __restrict__ x, const float* __restrict__ h1,
    const float* __restrict__ h2, const float* __restrict__ h3,
    const float* __restrict__ W, const float* __restrict__ bias,
    u16* __restrict__ out, int N){
  __shared__ float Ws[4*C*H];
  for(int u = threadIdx.x; u < 4*C*H; u += 256) Ws[u] = W[u];
  __syncthreads();
  const long long total = (long long)N * H;
  for(long long t = (long long)blockIdx.x*blockDim.x + threadIdx.x; t < total;
      t += (long long)gridDim.x*blockDim.x){
    int i = (int)(t >> 7), j = (int)(t & 127);
    const float* xr = x + (size_t)i*C;
    const float* r1 = h1 + (size_t)i*8;
    const float* r2 = h2 + (size_t)i*8;
    const float* r3 = h3 + (size_t)i*8;
    float acc = bias[j];
    #pragma unroll
    for(int k = 0; k < C; k++) acc += xr[k] * Ws[k*H + j];
    #pragma unroll
    for(int k = 0; k < C; k++) acc += r1[k] * Ws[(C + k)*H + j];
    #pragma unroll
    for(int k = 0; k < C; k++) acc += r2[k] * Ws[(2*C + k)*H + j];
    #pragma unroll
    for(int k = 0; k < C; k++) acc += r3[k] * Ws[(3*C + k)*H + j];
    out[t] = f2bf(fmaxf(acc, 0.f));
  }
}

// ---------------------------------------------------------------- fused SAGE (gather + dual-GEMM)

// out = relu( mean_{nbr} G[nbr] @ Wl + X @ Wr + bl ), all bf16, f32 accum.
// Block = 4 waves x 16 rows. Gather is WAVE-COOPERATIVE row-at-a-time (all 64
// lanes on one neighbor list, lane = 2 cols, 8-deep unroll -> no divergence);
// per-wave LDS transpose buf Tr[16][68] reshapes means into MFMA A-frags
// (68-u32 row stride keeps ds_read_b128 16B-aligned).
__global__ __launch_bounds__(256) void sage_fused(
    const u16* __restrict__ G, const u16* __restrict__ X,
    const int* __restrict__ rowp, const int* __restrict__ col,
    const u16* __restrict__ WbR, const u16* __restrict__ WbL,
    const float* __restrict__ bl, u16* __restrict__ out, int N){
  __shared__ u16 Ws[H * H];           // 32 KB, staged twice (Wr then Wl)
  __shared__ unsigned Tr[4][16][68];  // 17 KB, per-wave agg transpose

  const int t = threadIdx.x;
  const int lane = t & 63;
  const int wib = t >> 6;
  const int m0 = (blockIdx.x * 4 + wib) * 16;
  const int r16 = lane & 15;
  const int kg  = (lane >> 4) * 8;
  const bool active = (m0 < N);

  // ---- stage Wr (swizzled: byte ^= (col&7)<<4)
  for(int u = t; u < H*H/8; u += 256){
    bf16x8 v = *(const bf16x8*)&WbR[u*8];
    int c = u >> 4, kb = (u & 15) * 16;
    *(bf16x8*)((char*)Ws + c*256 + (kb ^ ((c & 7) << 4))) = v;
  }
  __syncthreads();

  f32x4 acc[8];
  #pragma unroll
  for(int tt = 0; tt < 8; tt++) acc[tt] = (f32x4){0.f,0.f,0.f,0.f};

  // ---- X phase: acc += X @ Wr
  if(active){
    const int row = m0 + r16;
    #pragma unroll
    for(int k0c = 0; k0c < 4; k0c++){
      int k0 = k0c * 32;
      bf16x8 af;
      if(row < N) af = *(const bf16x8*)&X[(size_t)row*H + k0 + kg];
      else        af = (bf16x8){0,0,0,0,0,0,0,0};
      #pragma unroll
      for(int tt = 0; tt < 8; tt++){
        int c = tt*16 + r16;
        int kb = (k0 + kg)*2;
        bf16x8 bf = *(const bf16x8*)((char*)Ws + c*256 + (kb ^ ((c & 7) << 4)));
        acc[tt] = __builtin_amdgcn_mfma_f32_16x16x32_bf16(af, bf, acc[tt], 0, 0, 0);
      }
    }
  }
  __syncthreads();

  // ---- stage Wl
  for(int u = t; u < H*H/8; u += 256){
    bf16x8 v = *(const bf16x8*)&WbL[u*8];
    int c = u >> 4, kb = (u & 15) * 16;
    *(bf16x8*)((char*)Ws + c*256 + (kb ^ ((c & 7) << 4))) = v;
  }
  __syncthreads();

  if(active){
    // ---- gather: wave-cooperative, one row at a time (lane = cols 2l,2l+1)
    for(int r = 0; r < 16; r++){
      int row = m0 + r;
      unsigned packed = 0;
      if(row < N){
        int b = rowp[row], e = rowp[row+1];
        float xs[8], ys[8];
        #pragma unroll
        for(int j = 0; j < 8; j++){ xs[j] = 0.f; ys[j] = 0.f; }
        int p = b;
        for(; p + 8 <= e; p += 8){
          unsigned v[8];
          #pragma unroll
          for(int j = 0; j < 8; j++)
            v[j] = *(const unsigned*)&G[(size_t)col[p + j]*H + lane*2];
          #pragma unroll
          for(int j = 0; j < 8; j++){ xs[j] += bflo(v[j]); ys[j] += bfhi(v[j]); }
        }
        for(; p < e; p++){
          unsigned v = *(const unsigned*)&G[(size_t)col[p]*H + lane*2];
          xs[0] += bflo(v); ys[0] += bfhi(v);
        }
        float sx = (xs[0]+xs[1])+(xs[2]+xs[3])+((xs[4]+xs[5])+(xs[6]+xs[7]));
        float sy = (ys[0]+ys[1])+(ys[2]+ys[3])+((ys[4]+ys[5])+(ys[6]+ys[7]));
        float inv = 1.f / fmaxf((float)(e - b), 1.f);
        packed = pack2(sx*inv, sy*inv);
      }
      Tr[wib][r][lane] = packed;
    }

    // ---- agg phase: acc += mean @ Wl (A-frags from Tr)
    #pragma unroll
    for(int kc = 0; kc < 4; kc++){
      bf16x8 agb = *(const bf16x8*)&Tr[wib][r16][(lane >> 4)*4 + kc*16];
      int kb = (kc*32 + kg)*2;
      #pragma unroll
      for(int tt = 0; tt < 8; tt++){
        int c = tt*16 + r16;
        bf16x8 bf = *(const bf16x8*)((char*)Ws + c*256 + (kb ^ ((c & 7) << 4)));
        acc[tt] = __builtin_amdgcn_mfma_f32_16x16x32_bf16(agb, bf, acc[tt], 0, 0, 0);
      }
    }

    // ---- epilogue
    const int orow = m0 + (lane >> 4) * 4;
    #pragma unroll
    for(int tt = 0; tt < 8; tt++){
      int c = tt*16 + r16;
      float bb = bl[c];
      #pragma unroll
      for(int r = 0; r < 4; r++){
        if(orow + r < N){
          float v = fmaxf(acc[tt][r] + bb, 0.f);
          out[(size_t)(orow + r)*H + c] = f2bf(v);
        }
      }
    }
  }
}

// ---------------------------------------------------------------- single-matrix MFMA (hs = gx @ Wsrc)

__global__ __launch_bounds__(256) void gemm_mfma(
    const u16* __restrict__ x, const u16* __restrict__ Wb,
    u16* __restrict__ out, int N){
  __shared__ u16 Ws[H * H];
  const int t = threadIdx.x;
  for(int u = t; u < H*H/8; u += 256){
    bf16x8 v = *(const bf16x8*)&Wb[u*8];
    int c = u >> 4, kb = (u & 15) * 16;
    *(bf16x8*)((char*)Ws + c*256 + (kb ^ ((c & 7) << 4))) = v;
  }
  __syncthreads();

  const int lane = t & 63;
  const int wib = t >> 6;
  const int m0 = (blockIdx.x * 4 + wib) * 32;
  if(m0 >= N) return;
  const int r16 = lane & 15;
  const int kg = (lane >> 4) * 8;

  f32x4 acc[2][8];
  #pragma unroll
  for(int rt = 0; rt < 2; rt++)
    #pragma unroll
    for(int tt = 0; tt < 8; tt++) acc[rt][tt] = (f32x4){0.f,0.f,0.f,0.f};

  #pragma unroll
  for(int k0c = 0; k0c < 4; k0c++){
    int k0 = k0c * 32;
    bf16x8 af[2];
    #pragma unroll
    for(int rt = 0; rt < 2; rt++){
      int row = m0 + rt*16 + r16;
      if(row < N) af[rt] = *(const bf16x8*)&x[(size_t)row*H + k0 + kg];
      else        af[rt] = (bf16x8){0,0,0,0,0,0,0,0};
    }
    #pragma unroll
    for(int tt = 0; tt < 8; tt++){
      int c = tt*16 + r16;
      int kb = (k0 + kg)*2;
      bf16x8 bf = *(const bf16x8*)((char*)Ws + c*256 + (kb ^ ((c & 7) << 4)));
      acc[0][tt] = __builtin_amdgcn_mfma_f32_16x16x32_bf16(af[0], bf, acc[0][tt], 0, 0, 0);
      acc[1][tt] = __builtin_amdgcn_mfma_f32_16x16x32_bf16(af[1], bf, acc[1][tt], 0, 0, 0);
    }
  }

  #pragma unroll
  for(int rt = 0; rt < 2; rt++){
    const int orow = m0 + rt*16 + (lane >> 4) * 4;
    #pragma unroll
    for(int tt = 0; tt < 8; tt++){
      int c = tt*16 + r16;
      #pragma unroll
      for(int r = 0; r < 4; r++){
        if(orow + r < N)
          out[(size_t)(orow + r)*H + c] = f2bf(acc[rt][tt][r]);
      }
    }
  }
}

// ---------------------------------------------------------------- GAT

__global__ void rowdot_bf(const u16* __restrict__ x, const float* __restrict__ v,
                          float* __restrict__ out, int N){
  int lane = threadIdx.x & 63;
  int w = (blockIdx.x*blockDim.x + threadIdx.x) >> 6;
  int nw = (gridDim.x*blockDim.x) >> 6;
  for(int i = w; i < N; i += nw){
    unsigned u = *(const unsigned*)&x[(size_t)i*H + lane*2];
    float acc = bflo(u)*v[lane*2] + bfhi(u)*v[lane*2 + 1];
    acc = waveReduceSum(acc);
    if(lane == 0) out[i] = acc;
  }
}

__global__ void gat_fused(const int* __restrict__ rowp, const int* __restrict__ colv,
                          const float* __restrict__ attrp, const float* __restrict__ av,
                          const float* __restrict__ ad, const float* __restrict__ cptr,
                          const u16* __restrict__ hs, const float* __restrict__ bias,
                          u16* __restrict__ out, int N){
  const float c = cptr[0];
  int lane = threadIdx.x & 63;
  int w = (blockIdx.x*blockDim.x + threadIdx.x) >> 6;
  int nw = (gridDim.x*blockDim.x) >> 6;
  for(int i = w; i < N; i += nw){
    int b = rowp[i], e = rowp[i+1];
    float adi = ad[i];
    float accx0 = 0.f, accy0 = 0.f, accx1 = 0.f, accy1 = 0.f;
    float sume = 0.f;
    int p = b;
    for(; p + 2 <= e; p += 2){
      int s0 = colv[p], s1 = colv[p+1];
      float a0 = av[s0] + adi + attrp[p] * c;
      float a1 = av[s1] + adi + attrp[p+1] * c;
      a0 = a0 > 0.f ? a0 : 0.2f * a0;
      a1 = a1 > 0.f ? a1 : 0.2f * a1;
      float e0 = __expf(a0), e1 = __expf(a1);
      unsigned v0 = *(const unsigned*)&hs[(size_t)s0*H + lane*2];
      unsigned v1 = *(const unsigned*)&hs[(size_t)s1*H + lane*2];
      accx0 += e0 * bflo(v0); accy0 += e0 * bfhi(v0);
      accx1 += e1 * bflo(v1); accy1 += e1 * bfhi(v1);
      sume += e0 + e1;
    }
    if(p < e){
      int s0 = colv[p];
      float a0 = av[s0] + adi + attrp[p] * c;
      a0 = a0 > 0.f ? a0 : 0.2f * a0;
      float e0 = __expf(a0);
      unsigned v0 = *(const unsigned*)&hs[(size_t)s0*H + lane*2];
      accx0 += e0 * bflo(v0); accy0 += e0 * bfhi(v0);
      sume += e0;
    }
    float rd = 1.f / fmaxf(sume, 1e-16f);
    float ox = fmaxf((accx0 + accx1) * rd + bias[lane*2],     0.f);
    float oy = fmaxf((accy0 + accy1) * rd + bias[lane*2 + 1], 0.f);
    *(unsigned*)&out[(size_t)i*H + lane*2] = pack2(ox, oy);
  }
}

__global__ void mlp_out_bf(const u16* __restrict__ x, const float* __restrict__ W,
                           const float* __restrict__ b, float* __restrict__ out, int N){
  int lane = threadIdx.x & 63;
  int w = (blockIdx.x*blockDim.x + threadIdx.x) >> 6;
  int nw = (gridDim.x*blockDim.x) >> 6;
  for(int i = w; i < N; i += nw){
    unsigned u = *(const unsigned*)&x[(size_t)i*H + lane*2];
    float acc = bflo(u)*W[lane*2] + bfhi(u)*W[lane*2 + 1];
    acc = waveReduceSum(acc);
    if(lane == 0) out[i] = acc + b[0];
  }
}

// ---------------------------------------------------------------- launch

extern "C" void kernel_launch(void* const* d_in, const int* in_sizes, int n_in,
                              void* d_out, int out_size, void* d_ws, size_t ws_size,
                              hipStream_t stream) {
  const float* game_x  = (const float*)d_in[0];
  const float* state_x = (const float*)d_in[1];
  const int*   e_vv    = (const int*)d_in[2];
  const int*   e_hist  = (const int*)d_in[4];
  const float* attr_h  = (const float*)d_in[5];
  const int*   e_in    = (const int*)d_in[6];
  const int*   e_ss    = (const int*)d_in[7];
  const float* tag1_W  = (const float*)d_in[8];
  const float* tag1_b  = (const float*)d_in[9];
  const float* tag2_W  = (const float*)d_in[10];
  const float* tag2_b  = (const float*)d_in[11];
  const float* sage_Wl = (const float*)d_in[12];
  const float* sage_bl = (const float*)d_in[13];
  const float* sage_Wr = (const float*)d_in[14];
  const float* gat_Wsrc= (const float*)d_in[15];
  const float* gat_Wdst= (const float*)d_in[16];
  const float* gat_We  = (const float*)d_in[17];
  const float* gat_asrc= (const float*)d_in[18];
  const float* gat_adst= (const float*)d_in[19];
  const float* gat_ae  = (const float*)d_in[20];
  const float* gat_b   = (const float*)d_in[21];
  const float* mlp_W   = (const float*)d_in[22];
  const float* mlp_b   = (const float*)d_in[23];
  float* out = (float*)d_out;

  const int NV  = in_sizes[0] / 5;
  const int NS  = in_sizes[1] / 6;
  const int EVV = in_sizes[2] / 2;
  const int EH  = in_sizes[4] / 2;
  const int EIN = in_sizes[6] / 2;
  const int ESS = in_sizes[7] / 2;

  const int* vv_src = e_vv;   const int* vv_dst = e_vv + EVV;
  const int* eh_src = e_hist; const int* eh_dst = e_hist + EH;
  const int* in_src = e_in;   const int* in_dst = e_in + EIN;
  const int* ss_src = e_ss;   const int* ss_dst = e_ss + ESS;

  const int NBv = (NV + 511) >> BSHIFT;
  const int NBs = (NS + 511) >> BSHIFT;
  const int capvv = (EVV / NBv) * 3 / 2 + 64;
  const int capss = (ESS / NBs) * 3 / 2 + 64;
  const int capeh = (EH  / NBs) * 3 / 2 + 64;
  const int capin = (EIN / NBs) * 3 / 2 + 64;

  char* wp = (char*)d_ws;
  auto alloc = [&](size_t bytes) -> void* {
    void* p = (void*)wp;
    wp += (bytes + 511) & ~size_t(511);
    return p;
  };
  u16* V0 = (u16*)alloc((size_t)NV*H*2);
  u16* V1 = (u16*)alloc((size_t)NV*H*2);
  u16* S0 = (u16*)alloc((size_t)NS*H*2);
  u16* S1 = (u16*)alloc((size_t)NS*H*2);
  u16* Wb = (u16*)alloc((size_t)15*H*H*2);
  float* dinv_v = (float*)alloc((size_t)NV*4);
  float* dinv_s = (float*)alloc((size_t)NS*4);
  float* av   = (float*)alloc((size_t)NV*4);
  float* ad   = (float*)alloc((size_t)NS*4);
  float* xp5  = (float*)alloc((size_t)NV*8*4);
  float* h5a  = (float*)alloc((size_t)NV*8*4);
  float* h5b  = (float*)alloc((size_t)NV*8*4);
  float* h5c  = (float*)alloc((size_t)NV*8*4);
  float* xp6  = (float*)alloc((size_t)NS*8*4);
  float* h6a  = (float*)alloc((size_t)NS*8*4);
  float* h6b  = (float*)alloc((size_t)NS*8*4);
  float* h6c  = (float*)alloc((size_t)NS*8*4);
  float* wvec = (float*)alloc(H*4);
  float* cbuf = (float*)alloc(4);
  int* vv_rowp = (int*)alloc((size_t)(NV+1)*4);
  int* vv_col  = (int*)alloc((size_t)EVV*4);
  int* ss_rowp = (int*)alloc((size_t)(NS+1)*4);
  int* ss_col  = (int*)alloc((size_t)ESS*4);
  int* eh_rowp = (int*)alloc((size_t)(NS+1)*4);
  int* eh_col  = (int*)alloc((size_t)EH*4);
  float* eh_attr = (float*)alloc((size_t)EH*4);
  int* in_rowp = (int*)alloc((size_t)(NS+1)*4);
  int* in_col  = (int*)alloc((size_t)EIN*4);
  int2* vv_bp = (int2*)alloc((size_t)NBv*capvv*8);
  int2* ss_bp = (int2*)alloc((size_t)NBs*capss*8);
  int2* eh_bp = (int2*)alloc((size_t)NBs*capeh*8);
  int2* in_bp = (int2*)alloc((size_t)NBs*capin*8);
  float* eh_ba = (float*)alloc((size_t)NBs*capeh*4);
  int* bcur  = (int*)alloc(4*256*4);
  int* bbase = (int*)alloc(4*256*4);
  (void)ws_size; (void)n_in; (void)out_size;

  const int B = 256;
  #define GRID1(n) gridFor((long long)(n), B, 8192), B, 0, stream
  #define GRIDW(e) gridFor((long long)(e) * 64, B, 16384), B, 0, stream
  #define GEMM(n)  ((n) + 63) / 64, 256, 0, stream

  // ---- bucketed CSR build
  hipMemsetAsync(bcur, 0, 4*256*4, stream);
  part_kernel<false><<<(EVV + CH - 1)/CH, 256, 0, stream>>>(
      vv_src, vv_dst, nullptr, bcur + 0,   vv_bp, nullptr, EVV, capvv);
  part_kernel<false><<<(ESS + CH - 1)/CH, 256, 0, stream>>>(
      ss_src, ss_dst, nullptr, bcur + 256, ss_bp, nullptr, ESS, capss);
  part_kernel<true ><<<(EH  + CH - 1)/CH, 256, 0, stream>>>(
      eh_src, eh_dst, attr_h,  bcur + 512, eh_bp, eh_ba,   EH,  capeh);
  part_kernel<false><<<(EIN + CH - 1)/CH, 256, 0, stream>>>(
      in_src, in_dst, nullptr, bcur + 768, in_bp, nullptr, EIN, capin);
  bucket_scan<<<4, 256, 0, stream>>>(bcur, bbase, vv_rowp, ss_rowp, eh_rowp, in_rowp,
                                     NV, NS, NS, NS);
  build_kernel<false,true ><<<NBv, 256, 0, stream>>>(
      vv_bp, nullptr, bcur + 0,   bbase + 0,   vv_rowp, vv_col, nullptr, dinv_v, capvv, NV);
  build_kernel<false,true ><<<NBs, 256, 0, stream>>>(
      ss_bp, nullptr, bcur + 256, bbase + 256, ss_rowp, ss_col, nullptr, dinv_s, capss, NS);
  build_kernel<true ,false><<<NBs, 256, 0, stream>>>(
      eh_bp, eh_ba,   bcur + 512, bbase + 512, eh_rowp, eh_col, eh_attr, nullptr, capeh, NS);
  build_kernel<false,false><<<NBs, 256, 0, stream>>>(
      in_bp, nullptr, bcur + 768, bbase + 768, in_rowp, in_col, nullptr, nullptr, capin, NS);

  // ---- weight prep
  cvt_weights<<<GRID1(15*H*H)>>>(sage_Wl, sage_Wr, gat_Wsrc, Wb);
  mat_vec_row<<<1, 128, 0, stream>>>(gat_Wdst, gat_adst, wvec);
  dot128<<<1, 64, 0, stream>>>(gat_We, gat_ae, cbuf);

  #define WBL(l) (Wb + ((size_t)(l) << 14))
  #define WBR(l) (Wb + ((size_t)(7 + (l)) << 14))

  // ---- TAG1 (game tower) -> V0
  pack_rows<5><<<GRID1(NV)>>>(game_x, dinv_v, xp5, NV);
  csr_tag_hop8<5><<<GRID1(NV)>>>(vv_rowp, vv_col, xp5, h5a, NV);
  csr_tag_hop8<5><<<GRID1(NV)>>>(vv_rowp, vv_col, h5a, h5b, NV);
  csr_tag_hop8<5><<<GRID1(NV)>>>(vv_rowp, vv_col, h5b, h5c, NV);
  tag_fuse<5><<<GRID1((long long)NV*H)>>>(game_x, h5a, h5b, h5c, tag1_W, tag1_b, V0, NV);

  // ---- SAGE 0,1 on vv (ping-pong V0 -> V1 -> V0)
  sage_fused<<<GEMM(NV)>>>(V0, V0, vv_rowp, vv_col, WBR(0), WBL(0),
                           sage_bl + 0*H, V1, NV);
  sage_fused<<<GEMM(NV)>>>(V1, V1, vv_rowp, vv_col, WBR(1), WBL(1),
                           sage_bl + 1*H, V0, NV);          // gx = V0

  // ---- TAG2 (state tower) -> S0
  pack_rows<6><<<GRID1(NS)>>>(state_x, dinv_s, xp6, NS);
  csr_tag_hop8<6><<<GRID1(NS)>>>(ss_rowp, ss_col, xp6, h6a, NS);
  csr_tag_hop8<6><<<GRID1(NS)>>>(ss_rowp, ss_col, h6a, h6b, NS);
  csr_tag_hop8<6><<<GRID1(NS)>>>(ss_rowp, ss_col, h6b, h6c, NS);
  tag_fuse<6><<<GRID1((long long)NS*H)>>>(state_x, h6a, h6b, h6c, tag2_W, tag2_b, S0, NS);

  // ---- SAGE 2,3 on ss (S0 -> S1 -> S0)
  sage_fused<<<GEMM(NS)>>>(S0, S0, ss_rowp, ss_col, WBR(2), WBL(2),
                           sage_bl + 2*H, S1, NS);
  sage_fused<<<GEMM(NS)>>>(S1, S1, ss_rowp, ss_col, WBR(3), WBL(3),
                           sage_bl + 3*H, S0, NS);          // sx = S0

  // ---- GAT (gx -> sx) : hist -> S1
  gemm_mfma<<<((NV + 127)/128), 256, 0, stream>>>(V0, Wb + ((size_t)14 << 14), V1, NV);
  rowdot_bf<<<GRIDW(NV)>>>(V1, gat_asrc, av, NV);
  rowdot_bf<<<GRIDW(NS)>>>(S0, wvec, ad, NS);                     // ad = sx @ (Wdst@adst)
  gat_fused<<<GRIDW(NS)>>>(eh_rowp, eh_col, eh_attr, av, ad, cbuf, V1, gat_b, S1, NS);

  // ---- SAGE4: gather gx over in-CSR, x_dst = hist(S1) -> S0
  sage_fused<<<GEMM(NS)>>>(V0, S1, in_rowp, in_col, WBR(4), WBL(4),
                           sage_bl + 4*H, S0, NS);

  // ---- SAGE 5,6 on ss (S0 -> S1 -> S0)
  sage_fused<<<GEMM(NS)>>>(S0, S0, ss_rowp, ss_col, WBR(5), WBL(5),
                           sage_bl + 5*H, S1, NS);
  sage_fused<<<GEMM(NS)>>>(S1, S1, ss_rowp, ss_col, WBR(6), WBL(6),
                           sage_bl + 6*H, S0, NS);

  // ---- final MLP -> d_out (f32)
  mlp_out_bf<<<GRIDW(NS)>>>(S0, mlp_W, mlp_b, out, NS);

  #undef GRID1
  #undef GRIDW
  #undef GEMM
  #undef WBL
  #undef WBR
}

// Round 12
// 901.599 us; speedup vs baseline: 1.4672x; 1.4672x over previous
//
#include <hip/hip_runtime.h>

#define H 128
typedef unsigned short u16;
typedef __attribute__((ext_vector_type(8))) short bf16x8;
typedef __attribute__((ext_vector_type(4))) float f32x4;

// ---------------------------------------------------------------- utilities

static inline int gridFor(long long work, int block, int cap = 16384){
  long long g = (work + block - 1) / block;
  if (g > cap) g = cap;
  if (g < 1) g = 1;
  return (int)g;
}

__device__ __forceinline__ float waveReduceSum(float v){
  #pragma unroll
  for(int off = 32; off > 0; off >>= 1) v += __shfl_down(v, off);
  return v;
}

__device__ __forceinline__ float bflo(unsigned v){ return __uint_as_float(v << 16); }
__device__ __forceinline__ float bfhi(unsigned v){ return __uint_as_float(v & 0xffff0000u); }
__device__ __forceinline__ u16 f2bf(float f){
  unsigned u = __float_as_uint(f);
  return (u16)((u + 0x7fffu + ((u >> 16) & 1u)) >> 16);
}
__device__ __forceinline__ unsigned pack2(float lo, float hi){
  return (unsigned)f2bf(lo) | ((unsigned)f2bf(hi) << 16);
}

// ---------------------------------------------------------------- bucketed CSR build
#define BSHIFT 9
#define CH 2048

template<bool HAS_ATTR>
__global__ __launch_bounds__(256) void part_kernel(
    const int* __restrict__ src, const int* __restrict__ dst,
    const float* __restrict__ attr, int* __restrict__ bcur,
    int2* __restrict__ bpairs, float* __restrict__ battr, int E, int cap){
  __shared__ int hist[256];
  __shared__ int hscan[256];
  __shared__ int hbase[256];
  __shared__ int hcur[256];
  __shared__ int2 buf[CH];
  __shared__ float abuf[HAS_ATTR ? CH : 1];

  const int t = threadIdx.x;
  const int e0 = blockIdx.x * CH;
  const int cnt = min(CH, E - e0);

  hist[t] = 0; hcur[t] = 0;
  __syncthreads();

  #pragma unroll
  for(int j = 0; j < 8; j++){
    int i = e0 + j*256 + t;
    if(i - e0 < cnt) atomicAdd(&hist[dst[i] >> BSHIFT], 1);
  }
  __syncthreads();

  {
    int v = hist[t];
    int lane = t & 63, wid = t >> 6;
    int incl = v;
    #pragma unroll
    for(int off = 1; off < 64; off <<= 1){
      int u = __shfl_up(incl, off);
      if(lane >= off) incl += u;
    }
    __shared__ int ws4[4];
    if(lane == 63) ws4[wid] = incl;
    __syncthreads();
    int wofs = 0;
    for(int wj = 0; wj < wid; wj++) wofs += ws4[wj];
    hscan[t] = wofs + incl - v;
    hbase[t] = (v > 0) ? atomicAdd(&bcur[t], v) : 0;
  }
  __syncthreads();

  #pragma unroll
  for(int j = 0; j < 8; j++){
    int i = e0 + j*256 + t;
    if(i - e0 < cnt){
      int d = dst[i], s = src[i];
      int b = d >> BSHIFT;
      int lp = atomicAdd(&hcur[b], 1);
      int slot = hscan[b] + lp;
      buf[slot] = make_int2(d, s);
      if(HAS_ATTR) abuf[slot] = attr[i];
    }
  }
  __syncthreads();

  for(int u = t; u < cnt; u += 256){
    int2 pr = buf[u];
    int b = pr.x >> BSHIFT;
    int g = b * cap + hbase[b] + (u - hscan[b]);
    bpairs[g] = pr;
    if(HAS_ATTR) battr[g] = abuf[u];
  }
}

__global__ void bucket_scan(const int* __restrict__ bcur, int* __restrict__ bbase,
                            int* __restrict__ rp0, int* __restrict__ rp1,
                            int* __restrict__ rp2, int* __restrict__ rp3,
                            int n0, int n1, int n2, int n3){
  int g = blockIdx.x;
  int n = (g == 0) ? n0 : (g == 1) ? n1 : (g == 2) ? n2 : n3;
  int* rowp = (g == 0) ? rp0 : (g == 1) ? rp1 : (g == 2) ? rp2 : rp3;
  int NB = (n + 511) >> BSHIFT;
  int t = threadIdx.x;
  int v = (t < NB) ? bcur[g*256 + t] : 0;
  int lane = t & 63, wid = t >> 6;
  int incl = v;
  #pragma unroll
  for(int off = 1; off < 64; off <<= 1){
    int u = __shfl_up(incl, off);
    if(lane >= off) incl += u;
  }
  __shared__ int ws4[4];
  if(lane == 63) ws4[wid] = incl;
  __syncthreads();
  int wofs = 0;
  for(int wj = 0; wj < wid; wj++) wofs += ws4[wj];
  bbase[g*256 + t] = wofs + incl - v;
  if(t == 0) rowp[n] = ws4[0] + ws4[1] + ws4[2] + ws4[3];
}

template<bool HAS_ATTR, bool DINV>
__global__ __launch_bounds__(256) void build_kernel(
    const int2* __restrict__ bpairs, const float* __restrict__ battr,
    const int* __restrict__ bcur, const int* __restrict__ bbase,
    int* __restrict__ rowp, int* __restrict__ col, float* __restrict__ attrp,
    float* __restrict__ dinv, int cap, int n){
  __shared__ int hist[512];
  __shared__ int hcur[512];
  __shared__ int ws4[4];

  const int b = blockIdx.x;
  const int t = threadIdx.x;
  const int d0 = b << BSHIFT;
  const int dn = min(512, n - d0);
  const int cnt = bcur[b];
  const int base = bbase[b];
  const int2* ep = bpairs + (size_t)b * cap;

  hist[t] = 0; hist[t + 256] = 0;
  __syncthreads();
  for(int u = t; u < cnt; u += 256) atomicAdd(&hist[ep[u].x - d0], 1);
  __syncthreads();

  int a0 = hist[2*t], a1 = hist[2*t + 1];
  int s = a0 + a1;
  int lane = t & 63, wid = t >> 6;
  int incl = s;
  #pragma unroll
  for(int off = 1; off < 64; off <<= 1){
    int u = __shfl_up(incl, off);
    if(lane >= off) incl += u;
  }
  if(lane == 63) ws4[wid] = incl;
  __syncthreads();
  int wofs = 0;
  for(int wj = 0; wj < wid; wj++) wofs += ws4[wj];
  int excl = wofs + incl - s;
  __syncthreads();
  hcur[2*t] = excl; hcur[2*t + 1] = excl + a0;
  if(2*t < dn){
    rowp[d0 + 2*t] = base + excl;
    if(DINV) dinv[d0 + 2*t] = a0 > 0 ? rsqrtf((float)a0) : 0.f;
  }
  if(2*t + 1 < dn){
    rowp[d0 + 2*t + 1] = base + excl + a0;
    if(DINV) dinv[d0 + 2*t + 1] = a1 > 0 ? rsqrtf((float)a1) : 0.f;
  }
  __syncthreads();

  for(int u = t; u < cnt; u += 256){
    int2 pr = ep[u];
    int pos = base + atomicAdd(&hcur[pr.x - d0], 1);
    col[pos] = pr.y;
    if(HAS_ATTR) attrp[pos] = battr[(size_t)b * cap + u];
  }
}

// ---------------------------------------------------------------- degree-clustered permutation
// Groups rows of equal degree into runs (per block-bin reservation from one
// global cursor -> bijective perm; adjacent perm entries have equal degree).
__global__ __launch_bounds__(256) void deg_scatter(
    const int* __restrict__ rowp, int* __restrict__ gcur,
    int* __restrict__ perm, int n){
  __shared__ int lh[64], lbase[64], lcur[64];
  const int t = threadIdx.x;
  const int base = blockIdx.x * 4096;
  if(base >= n) return;
  const int cnt = min(4096, n - base);
  if(t < 64){ lh[t] = 0; lcur[t] = 0; }
  __syncthreads();
  for(int i = t; i < cnt; i += 256){
    int r = base + i;
    int d = min(rowp[r+1] - rowp[r], 63);
    atomicAdd(&lh[d], 1);
  }
  __syncthreads();
  if(t < 64) lbase[t] = (lh[t] > 0) ? atomicAdd(gcur, lh[t]) : 0;
  __syncthreads();
  for(int i = t; i < cnt; i += 256){
    int r = base + i;
    int d = min(rowp[r+1] - rowp[r], 63);
    int lp = atomicAdd(&lcur[d], 1);
    perm[lbase[d] + lp] = r;
  }
}

// ---------------------------------------------------------------- weights to bf16 frag-major

__global__ void cvt_weights(const float* __restrict__ Wl, const float* __restrict__ Wr,
                            const float* __restrict__ Wsrc, u16* __restrict__ Wb){
  const int total = 15 * H * H;
  for(int t = blockIdx.x*blockDim.x + threadIdx.x; t < total; t += gridDim.x*blockDim.x){
    int mat = t >> 14, idx = t & 16383;
    int k = idx >> 7, colj = idx & 127;
    const float* srcp = (mat < 7) ? (Wl + ((size_t)mat << 14))
                       : (mat < 14) ? (Wr + ((size_t)(mat - 7) << 14))
                       : Wsrc;
    Wb[((size_t)mat << 14) + (size_t)colj*H + k] = f2bf(srcp[idx]);
  }
}

__global__ void mat_vec_row(const float* __restrict__ W, const float* __restrict__ a,
                            float* __restrict__ outv){
  int k = threadIdx.x;
  if(k < H){
    float s = 0.f;
    for(int j = 0; j < H; j++) s += W[(size_t)k*H + j] * a[j];
    outv[k] = s;
  }
}

__global__ void dot128(const float* __restrict__ a, const float* __restrict__ b,
                       float* __restrict__ o){
  int l = threadIdx.x;
  float acc = a[l]*b[l] + a[l+64]*b[l+64];
  acc = waveReduceSum(acc);
  if(l == 0) o[0] = acc;
}

// ---------------------------------------------------------------- TAG (padded 8-float rows, dinv in slot 7)

template<int C>
__global__ void pack_rows(const float* __restrict__ x, const float* __restrict__ dinv,
                          float* __restrict__ xp, int N){
  for(int i = blockIdx.x*blockDim.x + threadIdx.x; i < N; i += gridDim.x*blockDim.x){
    #pragma unroll
    for(int k = 0; k < C; k++) xp[(size_t)i*8 + k] = x[(size_t)i*C + k];
    xp[(size_t)i*8 + 7] = dinv[i];
  }
}

template<int C>
__global__ void csr_tag_hop8(const int* __restrict__ rowp, const int* __restrict__ col,
                             const float* __restrict__ hin, float* __restrict__ hout, int N){
  for(int i = blockIdx.x*blockDim.x + threadIdx.x; i < N; i += gridDim.x*blockDim.x){
    int b = rowp[i], e = rowp[i+1];
    float dd = hin[(size_t)i*8 + 7];
    float acc0[C], acc1[C];
    #pragma unroll
    for(int k = 0; k < C; k++){ acc0[k] = 0.f; acc1[k] = 0.f; }
    int p = b;
    for(; p + 2 <= e; p += 2){
      const float* r0 = &hin[(size_t)col[p]   * 8];
      const float* r1 = &hin[(size_t)col[p+1] * 8];
      float w0 = r0[7] * dd, w1 = r1[7] * dd;
      #pragma unroll
      for(int k = 0; k < C; k++){
        acc0[k] += r0[k] * w0;
        acc1[k] += r1[k] * w1;
      }
    }
    if(p < e){
      const float* r0 = &hin[(size_t)col[p] * 8];
      float w0 = r0[7] * dd;
      #pragma unroll
      for(int k = 0; k < C; k++) acc0[k] += r0[k] * w0;
    }
    #pragma unroll
    for(int k = 0; k < C; k++) hout[(size_t)i*8 + k] = acc0[k] + acc1[k];
    hout[(size_t)i*8 + 7] = dd;
  }
}

template<int C>
__global__ __launch_bounds__(256) void tag_fuse(
    const float* __restrict__ x, const float* __restrict__ h1,
    const float* __restrict__ h2, const float* __restrict__ h3,
    const float* __restrict__ W, const float* __restrict__ bias,
    u16* __restrict__ out, int N){
  __shared__ float Ws[4*C*H];
  for(int u = threadIdx.x; u < 4*C*H; u += 256) Ws[u] = W[u];
  __syncthreads();
  const long long total = (long long)N * H;
  for(long long t = (long long)blockIdx.x*blockDim.x + threadIdx.x; t < total;
      t += (long long)gridDim.x*blockDim.x){
    int i = (int)(t >> 7), j = (int)(t & 127);
    const float* xr = x + (size_t)i*C;
    const float* r1 = h1 + (size_t)i*8;
    const float* r2 = h2 + (size_t)i*8;
    const float* r3 = h3 + (size_t)i*8;
    float acc = bias[j];
    #pragma unroll
    for(int k = 0; k < C; k++) acc += xr[k] * Ws[k*H + j];
    #pragma unroll
    for(int k = 0; k < C; k++) acc += r1[k] * Ws[(C + k)*H + j];
    #pragma unroll
    for(int k = 0; k < C; k++) acc += r2[k] * Ws[(2*C + k)*H + j];
    #pragma unroll
    for(int k = 0; k < C; k++) acc += r3[k] * Ws[(3*C + k)*H + j];
    out[t] = f2bf(fmaxf(acc, 0.f));
  }
}

// ---------------------------------------------------------------- fused SAGE (gather + dual-GEMM)

// out = relu( mean_{nbr} G[nbr] @ Wl + X @ Wr + bl ), all bf16, f32 accum.
// Block = 4 waves x 16 rows. Per-lane divergent gather (16 rows in flight per
// wave — round-11 showed cooperative/serial is 2x worse) with 2-deep neighbor
// unroll; PERM clusters equal-degree rows so the 16 lanes have uniform trip
// counts (kills the ~1.65x exec-mask waste). perm is a bijection; all
// row-addressed accesses (X, gather, out) go through it -> numerics unchanged.
__global__ __launch_bounds__(256) void sage_fused(
    const u16* __restrict__ G, const u16* __restrict__ X,
    const int* __restrict__ rowp, const int* __restrict__ col,
    const int* __restrict__ perm,
    const u16* __restrict__ WbR, const u16* __restrict__ WbL,
    const float* __restrict__ bl, u16* __restrict__ out, int N){
  __shared__ u16 Ws[H * H];   // 32 KB, staged twice (Wr then Wl)

  const int t = threadIdx.x;
  const int lane = t & 63;
  const int wib = t >> 6;
  const int m0 = (blockIdx.x * 4 + wib) * 16;
  const int r16 = lane & 15;
  const int kg  = (lane >> 4) * 8;
  const bool active = (m0 < N);
  const int arow = (m0 + r16 < N) ? perm[m0 + r16] : -1;

  // ---- stage Wr (swizzled: byte ^= (col&7)<<4)
  for(int u = t; u < H*H/8; u += 256){
    bf16x8 v = *(const bf16x8*)&WbR[u*8];
    int c = u >> 4, kb = (u & 15) * 16;
    *(bf16x8*)((char*)Ws + c*256 + (kb ^ ((c & 7) << 4))) = v;
  }
  __syncthreads();

  f32x4 acc[8];
  #pragma unroll
  for(int tt = 0; tt < 8; tt++) acc[tt] = (f32x4){0.f,0.f,0.f,0.f};

  // ---- X phase: acc += X @ Wr
  if(active){
    #pragma unroll
    for(int k0c = 0; k0c < 4; k0c++){
      int k0 = k0c * 32;
      bf16x8 af;
      if(arow >= 0) af = *(const bf16x8*)&X[(size_t)arow*H + k0 + kg];
      else          af = (bf16x8){0,0,0,0,0,0,0,0};
      #pragma unroll
      for(int tt = 0; tt < 8; tt++){
        int c = tt*16 + r16;
        int kb = (k0 + kg)*2;
        bf16x8 bf = *(const bf16x8*)((char*)Ws + c*256 + (kb ^ ((c & 7) << 4)));
        acc[tt] = __builtin_amdgcn_mfma_f32_16x16x32_bf16(af, bf, acc[tt], 0, 0, 0);
      }
    }
  }
  __syncthreads();

  // ---- stage Wl
  for(int u = t; u < H*H/8; u += 256){
    bf16x8 v = *(const bf16x8*)&WbL[u*8];
    int c = u >> 4, kb = (u & 15) * 16;
    *(bf16x8*)((char*)Ws + c*256 + (kb ^ ((c & 7) << 4))) = v;
  }
  __syncthreads();

  if(active){
    // ---- gather: per-lane row walk, 2-deep neighbor unroll
    float ag[4][8];
    #pragma unroll
    for(int kc = 0; kc < 4; kc++)
      #pragma unroll
      for(int j = 0; j < 8; j++) ag[kc][j] = 0.f;

    if(arow >= 0){
      int b = rowp[arow], e = rowp[arow+1];
      int p = b;
      for(; p + 2 <= e; p += 2){
        int s0 = col[p], s1 = col[p+1];
        const u16* g0 = &G[(size_t)s0*H + kg];
        const u16* g1 = &G[(size_t)s1*H + kg];
        #pragma unroll
        for(int kc = 0; kc < 4; kc++){
          bf16x8 v0 = *(const bf16x8*)(g0 + kc*32);
          bf16x8 v1 = *(const bf16x8*)(g1 + kc*32);
          const unsigned* u0 = (const unsigned*)&v0;
          const unsigned* u1 = (const unsigned*)&v1;
          #pragma unroll
          for(int q = 0; q < 4; q++){
            ag[kc][2*q]   += bflo(u0[q]) + bflo(u1[q]);
            ag[kc][2*q+1] += bfhi(u0[q]) + bfhi(u1[q]);
          }
        }
      }
      if(p < e){
        const u16* g0 = &G[(size_t)col[p]*H + kg];
        #pragma unroll
        for(int kc = 0; kc < 4; kc++){
          bf16x8 v0 = *(const bf16x8*)(g0 + kc*32);
          const unsigned* u0 = (const unsigned*)&v0;
          #pragma unroll
          for(int q = 0; q < 4; q++){
            ag[kc][2*q]   += bflo(u0[q]);
            ag[kc][2*q+1] += bfhi(u0[q]);
          }
        }
      }
      float inv = 1.f / fmaxf((float)(e - b), 1.f);
      #pragma unroll
      for(int kc = 0; kc < 4; kc++)
        #pragma unroll
        for(int j = 0; j < 8; j++) ag[kc][j] *= inv;
    }

    // ---- agg phase: acc += mean @ Wl
    #pragma unroll
    for(int kc = 0; kc < 4; kc++){
      unsigned uu[4];
      #pragma unroll
      for(int q = 0; q < 4; q++) uu[q] = pack2(ag[kc][2*q], ag[kc][2*q+1]);
      bf16x8 agb = *(bf16x8*)uu;
      int kb = (kc*32 + kg)*2;
      #pragma unroll
      for(int tt = 0; tt < 8; tt++){
        int c = tt*16 + r16;
        bf16x8 bf = *(const bf16x8*)((char*)Ws + c*256 + (kb ^ ((c & 7) << 4)));
        acc[tt] = __builtin_amdgcn_mfma_f32_16x16x32_bf16(agb, bf, acc[tt], 0, 0, 0);
      }
    }

    // ---- epilogue (D rows -> perm)
    int op[4];
    #pragma unroll
    for(int r = 0; r < 4; r++){
      int oidx = m0 + (lane >> 4)*4 + r;
      op[r] = (oidx < N) ? perm[oidx] : -1;
    }
    #pragma unroll
    for(int tt = 0; tt < 8; tt++){
      int c = tt*16 + r16;
      float bb = bl[c];
      #pragma unroll
      for(int r = 0; r < 4; r++){
        if(op[r] >= 0){
          float v = fmaxf(acc[tt][r] + bb, 0.f);
          out[(size_t)op[r]*H + c] = f2bf(v);
        }
      }
    }
  }
}

// ---------------------------------------------------------------- single-matrix MFMA (hs = gx @ Wsrc)

__global__ __launch_bounds__(256) void gemm_mfma(
    const u16* __restrict__ x, const u16* __restrict__ Wb,
    u16* __restrict__ out, int N){
  __shared__ u16 Ws[H * H];
  const int t = threadIdx.x;
  for(int u = t; u < H*H/8; u += 256){
    bf16x8 v = *(const bf16x8*)&Wb[u*8];
    int c = u >> 4, kb = (u & 15) * 16;
    *(bf16x8*)((char*)Ws + c*256 + (kb ^ ((c & 7) << 4))) = v;
  }
  __syncthreads();

  const int lane = t & 63;
  const int wib = t >> 6;
  const int m0 = (blockIdx.x * 4 + wib) * 32;
  if(m0 >= N) return;
  const int r16 = lane & 15;
  const int kg = (lane >> 4) * 8;

  f32x4 acc[2][8];
  #pragma unroll
  for(int rt = 0; rt < 2; rt++)
    #pragma unroll
    for(int tt = 0; tt < 8; tt++) acc[rt][tt] = (f32x4){0.f,0.f,0.f,0.f};

  #pragma unroll
  for(int k0c = 0; k0c < 4; k0c++){
    int k0 = k0c * 32;
    bf16x8 af[2];
    #pragma unroll
    for(int rt = 0; rt < 2; rt++){
      int row = m0 + rt*16 + r16;
      if(row < N) af[rt] = *(const bf16x8*)&x[(size_t)row*H + k0 + kg];
      else        af[rt] = (bf16x8){0,0,0,0,0,0,0,0};
    }
    #pragma unroll
    for(int tt = 0; tt < 8; tt++){
      int c = tt*16 + r16;
      int kb = (k0 + kg)*2;
      bf16x8 bf = *(const bf16x8*)((char*)Ws + c*256 + (kb ^ ((c & 7) << 4)));
      acc[0][tt] = __builtin_amdgcn_mfma_f32_16x16x32_bf16(af[0], bf, acc[0][tt], 0, 0, 0);
      acc[1][tt] = __builtin_amdgcn_mfma_f32_16x16x32_bf16(af[1], bf, acc[1][tt], 0, 0, 0);
    }
  }

  #pragma unroll
  for(int rt = 0; rt < 2; rt++){
    const int orow = m0 + rt*16 + (lane >> 4) * 4;
    #pragma unroll
    for(int tt = 0; tt < 8; tt++){
      int c = tt*16 + r16;
      #pragma unroll
      for(int r = 0; r < 4; r++){
        if(orow + r < N)
          out[(size_t)(orow + r)*H + c] = f2bf(acc[rt][tt][r]);
      }
    }
  }
}

// ---------------------------------------------------------------- GAT

__global__ void rowdot_bf(const u16* __restrict__ x, const float* __restrict__ v,
                          float* __restrict__ out, int N){
  int lane = threadIdx.x & 63;
  int w = (blockIdx.x*blockDim.x + threadIdx.x) >> 6;
  int nw = (gridDim.x*blockDim.x) >> 6;
  for(int i = w; i < N; i += nw){
    unsigned u = *(const unsigned*)&x[(size_t)i*H + lane*2];
    float acc = bflo(u)*v[lane*2] + bfhi(u)*v[lane*2 + 1];
    acc = waveReduceSum(acc);
    if(lane == 0) out[i] = acc;
  }
}

__global__ void gat_fused(const int* __restrict__ rowp, const int* __restrict__ colv,
                          const float* __restrict__ attrp, const float* __restrict__ av,
                          const float* __restrict__ ad, const float* __restrict__ cptr,
                          const u16* __restrict__ hs, const float* __restrict__ bias,
                          u16* __restrict__ out, int N){
  const float c = cptr[0];
  int lane = threadIdx.x & 63;
  int w = (blockIdx.x*blockDim.x + threadIdx.x) >> 6;
  int nw = (gridDim.x*blockDim.x) >> 6;
  for(int i = w; i < N; i += nw){
    int b = rowp[i], e = rowp[i+1];
    float adi = ad[i];
    float accx0 = 0.f, accy0 = 0.f, accx1 = 0.f, accy1 = 0.f;
    float sume = 0.f;
    int p = b;
    for(; p + 2 <= e; p += 2){
      int s0 = colv[p], s1 = colv[p+1];
      float a0 = av[s0] + adi + attrp[p] * c;
      float a1 = av[s1] + adi + attrp[p+1] * c;
      a0 = a0 > 0.f ? a0 : 0.2f * a0;
      a1 = a1 > 0.f ? a1 : 0.2f * a1;
      float e0 = __expf(a0), e1 = __expf(a1);
      unsigned v0 = *(const unsigned*)&hs[(size_t)s0*H + lane*2];
      unsigned v1 = *(const unsigned*)&hs[(size_t)s1*H + lane*2];
      accx0 += e0 * bflo(v0); accy0 += e0 * bfhi(v0);
      accx1 += e1 * bflo(v1); accy1 += e1 * bfhi(v1);
      sume += e0 + e1;
    }
    if(p < e){
      int s0 = colv[p];
      float a0 = av[s0] + adi + attrp[p] * c;
      a0 = a0 > 0.f ? a0 : 0.2f * a0;
      float e0 = __expf(a0);
      unsigned v0 = *(const unsigned*)&hs[(size_t)s0*H + lane*2];
      accx0 += e0 * bflo(v0); accy0 += e0 * bfhi(v0);
      sume += e0;
    }
    float rd = 1.f / fmaxf(sume, 1e-16f);
    float ox = fmaxf((accx0 + accx1) * rd + bias[lane*2],     0.f);
    float oy = fmaxf((accy0 + accy1) * rd + bias[lane*2 + 1], 0.f);
    *(unsigned*)&out[(size_t)i*H + lane*2] = pack2(ox, oy);
  }
}

__global__ void mlp_out_bf(const u16* __restrict__ x, const float* __restrict__ W,
                           const float* __restrict__ b, float* __restrict__ out, int N){
  int lane = threadIdx.x & 63;
  int w = (blockIdx.x*blockDim.x + threadIdx.x) >> 6;
  int nw = (gridDim.x*blockDim.x) >> 6;
  for(int i = w; i < N; i += nw){
    unsigned u = *(const unsigned*)&x[(size_t)i*H + lane*2];
    float acc = bflo(u)*W[lane*2] + bfhi(u)*W[lane*2 + 1];
    acc = waveReduceSum(acc);
    if(lane == 0) out[i] = acc + b[0];
  }
}

// ---------------------------------------------------------------- launch

extern "C" void kernel_launch(void* const* d_in, const int* in_sizes, int n_in,
                              void* d_out, int out_size, void* d_ws, size_t ws_size,
                              hipStream_t stream) {
  const float* game_x  = (const float*)d_in[0];
  const float* state_x = (const float*)d_in[1];
  const int*   e_vv    = (const int*)d_in[2];
  const int*   e_hist  = (const int*)d_in[4];
  const float* attr_h  = (const float*)d_in[5];
  const int*   e_in    = (const int*)d_in[6];
  const int*   e_ss    = (const int*)d_in[7];
  const float* tag1_W  = (const float*)d_in[8];
  const float* tag1_b  = (const float*)d_in[9];
  const float* tag2_W  = (const float*)d_in[10];
  const float* tag2_b  = (const float*)d_in[11];
  const float* sage_Wl = (const float*)d_in[12];
  const float* sage_bl = (const float*)d_in[13];
  const float* sage_Wr = (const float*)d_in[14];
  const float* gat_Wsrc= (const float*)d_in[15];
  const float* gat_Wdst= (const float*)d_in[16];
  const float* gat_We  = (const float*)d_in[17];
  const float* gat_asrc= (const float*)d_in[18];
  const float* gat_adst= (const float*)d_in[19];
  const float* gat_ae  = (const float*)d_in[20];
  const float* gat_b   = (const float*)d_in[21];
  const float* mlp_W   = (const float*)d_in[22];
  const float* mlp_b   = (const float*)d_in[23];
  float* out = (float*)d_out;

  const int NV  = in_sizes[0] / 5;
  const int NS  = in_sizes[1] / 6;
  const int EVV = in_sizes[2] / 2;
  const int EH  = in_sizes[4] / 2;
  const int EIN = in_sizes[6] / 2;
  const int ESS = in_sizes[7] / 2;

  const int* vv_src = e_vv;   const int* vv_dst = e_vv + EVV;
  const int* eh_src = e_hist; const int* eh_dst = e_hist + EH;
  const int* in_src = e_in;   const int* in_dst = e_in + EIN;
  const int* ss_src = e_ss;   const int* ss_dst = e_ss + ESS;

  const int NBv = (NV + 511) >> BSHIFT;
  const int NBs = (NS + 511) >> BSHIFT;
  const int capvv = (EVV / NBv) * 3 / 2 + 64;
  const int capss = (ESS / NBs) * 3 / 2 + 64;
  const int capeh = (EH  / NBs) * 3 / 2 + 64;
  const int capin = (EIN / NBs) * 3 / 2 + 64;

  char* wp = (char*)d_ws;
  auto alloc = [&](size_t bytes) -> void* {
    void* p = (void*)wp;
    wp += (bytes + 511) & ~size_t(511);
    return p;
  };
  u16* V0 = (u16*)alloc((size_t)NV*H*2);
  u16* V1 = (u16*)alloc((size_t)NV*H*2);
  u16* S0 = (u16*)alloc((size_t)NS*H*2);
  u16* S1 = (u16*)alloc((size_t)NS*H*2);
  u16* Wb = (u16*)alloc((size_t)15*H*H*2);
  float* dinv_v = (float*)alloc((size_t)NV*4);
  float* dinv_s = (float*)alloc((size_t)NS*4);
  float* av   = (float*)alloc((size_t)NV*4);
  float* ad   = (float*)alloc((size_t)NS*4);
  float* xp5  = (float*)alloc((size_t)NV*8*4);
  float* h5a  = (float*)alloc((size_t)NV*8*4);
  float* h5b  = (float*)alloc((size_t)NV*8*4);
  float* h5c  = (float*)alloc((size_t)NV*8*4);
  float* xp6  = (float*)alloc((size_t)NS*8*4);
  float* h6a  = (float*)alloc((size_t)NS*8*4);
  float* h6b  = (float*)alloc((size_t)NS*8*4);
  float* h6c  = (float*)alloc((size_t)NS*8*4);
  float* wvec = (float*)alloc(H*4);
  float* cbuf = (float*)alloc(4);
  int* vv_rowp = (int*)alloc((size_t)(NV+1)*4);
  int* vv_col  = (int*)alloc((size_t)EVV*4);
  int* ss_rowp = (int*)alloc((size_t)(NS+1)*4);
  int* ss_col  = (int*)alloc((size_t)ESS*4);
  int* eh_rowp = (int*)alloc((size_t)(NS+1)*4);
  int* eh_col  = (int*)alloc((size_t)EH*4);
  float* eh_attr = (float*)alloc((size_t)EH*4);
  int* in_rowp = (int*)alloc((size_t)(NS+1)*4);
  int* in_col  = (int*)alloc((size_t)EIN*4);
  int* perm_vv = (int*)alloc((size_t)NV*4);
  int* perm_ss = (int*)alloc((size_t)NS*4);
  int* perm_in = (int*)alloc((size_t)NS*4);
  int2* vv_bp = (int2*)alloc((size_t)NBv*capvv*8);
  int2* ss_bp = (int2*)alloc((size_t)NBs*capss*8);
  int2* eh_bp = (int2*)alloc((size_t)NBs*capeh*8);
  int2* in_bp = (int2*)alloc((size_t)NBs*capin*8);
  float* eh_ba = (float*)alloc((size_t)NBs*capeh*4);
  int* bcur  = (int*)alloc(4*256*4);
  int* bbase = (int*)alloc(4*256*4);
  int* pcur  = (int*)alloc(3*4);
  (void)ws_size; (void)n_in; (void)out_size;

  const int B = 256;
  #define GRID1(n) gridFor((long long)(n), B, 8192), B, 0, stream
  #define GRIDW(e) gridFor((long long)(e) * 64, B, 16384), B, 0, stream
  #define GEMM(n)  ((n) + 63) / 64, 256, 0, stream

  // ---- bucketed CSR build
  hipMemsetAsync(bcur, 0, 4*256*4, stream);
  hipMemsetAsync(pcur, 0, 3*4, stream);
  part_kernel<false><<<(EVV + CH - 1)/CH, 256, 0, stream>>>(
      vv_src, vv_dst, nullptr, bcur + 0,   vv_bp, nullptr, EVV, capvv);
  part_kernel<false><<<(ESS + CH - 1)/CH, 256, 0, stream>>>(
      ss_src, ss_dst, nullptr, bcur + 256, ss_bp, nullptr, ESS, capss);
  part_kernel<true ><<<(EH  + CH - 1)/CH, 256, 0, stream>>>(
      eh_src, eh_dst, attr_h,  bcur + 512, eh_bp, eh_ba,   EH,  capeh);
  part_kernel<false><<<(EIN + CH - 1)/CH, 256, 0, stream>>>(
      in_src, in_dst, nullptr, bcur + 768, in_bp, nullptr, EIN, capin);
  bucket_scan<<<4, 256, 0, stream>>>(bcur, bbase, vv_rowp, ss_rowp, eh_rowp, in_rowp,
                                     NV, NS, NS, NS);
  build_kernel<false,true ><<<NBv, 256, 0, stream>>>(
      vv_bp, nullptr, bcur + 0,   bbase + 0,   vv_rowp, vv_col, nullptr, dinv_v, capvv, NV);
  build_kernel<false,true ><<<NBs, 256, 0, stream>>>(
      ss_bp, nullptr, bcur + 256, bbase + 256, ss_rowp, ss_col, nullptr, dinv_s, capss, NS);
  build_kernel<true ,false><<<NBs, 256, 0, stream>>>(
      eh_bp, eh_ba,   bcur + 512, bbase + 512, eh_rowp, eh_col, eh_attr, nullptr, capeh, NS);
  build_kernel<false,false><<<NBs, 256, 0, stream>>>(
      in_bp, nullptr, bcur + 768, bbase + 768, in_rowp, in_col, nullptr, nullptr, capin, NS);

  // ---- degree-clustered permutations (for sage_fused lane uniformity)
  deg_scatter<<<(NV + 4095)/4096, 256, 0, stream>>>(vv_rowp, pcur + 0, perm_vv, NV);
  deg_scatter<<<(NS + 4095)/4096, 256, 0, stream>>>(ss_rowp, pcur + 1, perm_ss, NS);
  deg_scatter<<<(NS + 4095)/4096, 256, 0, stream>>>(in_rowp, pcur + 2, perm_in, NS);

  // ---- weight prep
  cvt_weights<<<GRID1(15*H*H)>>>(sage_Wl, sage_Wr, gat_Wsrc, Wb);
  mat_vec_row<<<1, 128, 0, stream>>>(gat_Wdst, gat_adst, wvec);
  dot128<<<1, 64, 0, stream>>>(gat_We, gat_ae, cbuf);

  #define WBL(l) (Wb + ((size_t)(l) << 14))
  #define WBR(l) (Wb + ((size_t)(7 + (l)) << 14))

  // ---- TAG1 (game tower) -> V0
  pack_rows<5><<<GRID1(NV)>>>(game_x, dinv_v, xp5, NV);
  csr_tag_hop8<5><<<GRID1(NV)>>>(vv_rowp, vv_col, xp5, h5a, NV);
  csr_tag_hop8<5><<<GRID1(NV)>>>(vv_rowp, vv_col, h5a, h5b, NV);
  csr_tag_hop8<5><<<GRID1(NV)>>>(vv_rowp, vv_col, h5b, h5c, NV);
  tag_fuse<5><<<GRID1((long long)NV*H)>>>(game_x, h5a, h5b, h5c, tag1_W, tag1_b, V0, NV);

  // ---- SAGE 0,1 on vv (ping-pong V0 -> V1 -> V0)
  sage_fused<<<GEMM(NV)>>>(V0, V0, vv_rowp, vv_col, perm_vv, WBR(0), WBL(0),
                           sage_bl + 0*H, V1, NV);
  sage_fused<<<GEMM(NV)>>>(V1, V1, vv_rowp, vv_col, perm_vv, WBR(1), WBL(1),
                           sage_bl + 1*H, V0, NV);          // gx = V0

  // ---- TAG2 (state tower) -> S0
  pack_rows<6><<<GRID1(NS)>>>(state_x, dinv_s, xp6, NS);
  csr_tag_hop8<6><<<GRID1(NS)>>>(ss_rowp, ss_col, xp6, h6a, NS);
  csr_tag_hop8<6><<<GRID1(NS)>>>(ss_rowp, ss_col, h6a, h6b, NS);
  csr_tag_hop8<6><<<GRID1(NS)>>>(ss_rowp, ss_col, h6b, h6c, NS);
  tag_fuse<6><<<GRID1((long long)NS*H)>>>(state_x, h6a, h6b, h6c, tag2_W, tag2_b, S0, NS);

  // ---- SAGE 2,3 on ss (S0 -> S1 -> S0)
  sage_fused<<<GEMM(NS)>>>(S0, S0, ss_rowp, ss_col, perm_ss, WBR(2), WBL(2),
                           sage_bl + 2*H, S1, NS);
  sage_fused<<<GEMM(NS)>>>(S1, S1, ss_rowp, ss_col, perm_ss, WBR(3), WBL(3),
                           sage_bl + 3*H, S0, NS);          // sx = S0

  // ---- GAT (gx -> sx) : hist -> S1
  gemm_mfma<<<((NV + 127)/128), 256, 0, stream>>>(V0, Wb + ((size_t)14 << 14), V1, NV);
  rowdot_bf<<<GRIDW(NV)>>>(V1, gat_asrc, av, NV);
  rowdot_bf<<<GRIDW(NS)>>>(S0, wvec, ad, NS);                     // ad = sx @ (Wdst@adst)
  gat_fused<<<GRIDW(NS)>>>(eh_rowp, eh_col, eh_attr, av, ad, cbuf, V1, gat_b, S1, NS);

  // ---- SAGE4: gather gx over in-CSR, x_dst = hist(S1) -> S0
  sage_fused<<<GEMM(NS)>>>(V0, S1, in_rowp, in_col, perm_in, WBR(4), WBL(4),
                           sage_bl + 4*H, S0, NS);

  // ---- SAGE 5,6 on ss (S0 -> S1 -> S0)
  sage_fused<<<GEMM(NS)>>>(S0, S0, ss_rowp, ss_col, perm_ss, WBR(5), WBL(5),
                           sage_bl + 5*H, S1, NS);
  sage_fused<<<GEMM(NS)>>>(S1, S1, ss_rowp, ss_col, perm_ss, WBR(6), WBL(6),
                           sage_bl + 6*H, S0, NS);

  // ---- final MLP -> d_out (f32)
  mlp_out_bf<<<GRIDW(NS)>>>(S0, mlp_W, mlp_b, out, NS);

  #undef GRID1
  #undef GRIDW
  #undef GEMM
  #undef WBL
  #undef WBR
}

// Round 13
// 836.196 us; speedup vs baseline: 1.5819x; 1.0782x over previous
//
#include <hip/hip_runtime.h>

#define H 128
typedef unsigned short u16;
typedef __attribute__((ext_vector_type(8))) short bf16x8;
typedef __attribute__((ext_vector_type(4))) float f32x4;

// ---------------------------------------------------------------- utilities

static inline int gridFor(long long work, int block, int cap = 16384){
  long long g = (work + block - 1) / block;
  if (g > cap) g = cap;
  if (g < 1) g = 1;
  return (int)g;
}

__device__ __forceinline__ float waveReduceSum(float v){
  #pragma unroll
  for(int off = 32; off > 0; off >>= 1) v += __shfl_down(v, off);
  return v;
}

__device__ __forceinline__ float bflo(unsigned v){ return __uint_as_float(v << 16); }
__device__ __forceinline__ float bfhi(unsigned v){ return __uint_as_float(v & 0xffff0000u); }
__device__ __forceinline__ u16 f2bf(float f){
  unsigned u = __float_as_uint(f);
  return (u16)((u + 0x7fffu + ((u >> 16) & 1u)) >> 16);
}
__device__ __forceinline__ unsigned pack2(float lo, float hi){
  return (unsigned)f2bf(lo) | ((unsigned)f2bf(hi) << 16);
}

// ---------------------------------------------------------------- bucketed CSR build
#define BSHIFT 9
#define CH 2048

template<bool HAS_ATTR>
__global__ __launch_bounds__(256) void part_kernel(
    const int* __restrict__ src, const int* __restrict__ dst,
    const float* __restrict__ attr, int* __restrict__ bcur,
    int2* __restrict__ bpairs, float* __restrict__ battr, int E, int cap){
  __shared__ int hist[256];
  __shared__ int hscan[256];
  __shared__ int hbase[256];
  __shared__ int hcur[256];
  __shared__ int2 buf[CH];
  __shared__ float abuf[HAS_ATTR ? CH : 1];

  const int t = threadIdx.x;
  const int e0 = blockIdx.x * CH;
  const int cnt = min(CH, E - e0);

  hist[t] = 0; hcur[t] = 0;
  __syncthreads();

  #pragma unroll
  for(int j = 0; j < 8; j++){
    int i = e0 + j*256 + t;
    if(i - e0 < cnt) atomicAdd(&hist[dst[i] >> BSHIFT], 1);
  }
  __syncthreads();

  {
    int v = hist[t];
    int lane = t & 63, wid = t >> 6;
    int incl = v;
    #pragma unroll
    for(int off = 1; off < 64; off <<= 1){
      int u = __shfl_up(incl, off);
      if(lane >= off) incl += u;
    }
    __shared__ int ws4[4];
    if(lane == 63) ws4[wid] = incl;
    __syncthreads();
    int wofs = 0;
    for(int wj = 0; wj < wid; wj++) wofs += ws4[wj];
    hscan[t] = wofs + incl - v;
    hbase[t] = (v > 0) ? atomicAdd(&bcur[t], v) : 0;
  }
  __syncthreads();

  #pragma unroll
  for(int j = 0; j < 8; j++){
    int i = e0 + j*256 + t;
    if(i - e0 < cnt){
      int d = dst[i], s = src[i];
      int b = d >> BSHIFT;
      int lp = atomicAdd(&hcur[b], 1);
      int slot = hscan[b] + lp;
      buf[slot] = make_int2(d, s);
      if(HAS_ATTR) abuf[slot] = attr[i];
    }
  }
  __syncthreads();

  for(int u = t; u < cnt; u += 256){
    int2 pr = buf[u];
    int b = pr.x >> BSHIFT;
    int g = b * cap + hbase[b] + (u - hscan[b]);
    bpairs[g] = pr;
    if(HAS_ATTR) battr[g] = abuf[u];
  }
}

__global__ void bucket_scan(const int* __restrict__ bcur, int* __restrict__ bbase,
                            int* __restrict__ rp0, int* __restrict__ rp1,
                            int* __restrict__ rp2, int* __restrict__ rp3,
                            int n0, int n1, int n2, int n3){
  int g = blockIdx.x;
  int n = (g == 0) ? n0 : (g == 1) ? n1 : (g == 2) ? n2 : n3;
  int* rowp = (g == 0) ? rp0 : (g == 1) ? rp1 : (g == 2) ? rp2 : rp3;
  int NB = (n + 511) >> BSHIFT;
  int t = threadIdx.x;
  int v = (t < NB) ? bcur[g*256 + t] : 0;
  int lane = t & 63, wid = t >> 6;
  int incl = v;
  #pragma unroll
  for(int off = 1; off < 64; off <<= 1){
    int u = __shfl_up(incl, off);
    if(lane >= off) incl += u;
  }
  __shared__ int ws4[4];
  if(lane == 63) ws4[wid] = incl;
  __syncthreads();
  int wofs = 0;
  for(int wj = 0; wj < wid; wj++) wofs += ws4[wj];
  bbase[g*256 + t] = wofs + incl - v;
  if(t == 0) rowp[n] = ws4[0] + ws4[1] + ws4[2] + ws4[3];
}

template<bool HAS_ATTR, bool DINV>
__global__ __launch_bounds__(256) void build_kernel(
    const int2* __restrict__ bpairs, const float* __restrict__ battr,
    const int* __restrict__ bcur, const int* __restrict__ bbase,
    int* __restrict__ rowp, int* __restrict__ col, float* __restrict__ attrp,
    float* __restrict__ dinv, int cap, int n){
  __shared__ int hist[512];
  __shared__ int hcur[512];
  __shared__ int ws4[4];

  const int b = blockIdx.x;
  const int t = threadIdx.x;
  const int d0 = b << BSHIFT;
  const int dn = min(512, n - d0);
  const int cnt = bcur[b];
  const int base = bbase[b];
  const int2* ep = bpairs + (size_t)b * cap;

  hist[t] = 0; hist[t + 256] = 0;
  __syncthreads();
  for(int u = t; u < cnt; u += 256) atomicAdd(&hist[ep[u].x - d0], 1);
  __syncthreads();

  int a0 = hist[2*t], a1 = hist[2*t + 1];
  int s = a0 + a1;
  int lane = t & 63, wid = t >> 6;
  int incl = s;
  #pragma unroll
  for(int off = 1; off < 64; off <<= 1){
    int u = __shfl_up(incl, off);
    if(lane >= off) incl += u;
  }
  if(lane == 63) ws4[wid] = incl;
  __syncthreads();
  int wofs = 0;
  for(int wj = 0; wj < wid; wj++) wofs += ws4[wj];
  int excl = wofs + incl - s;
  __syncthreads();
  hcur[2*t] = excl; hcur[2*t + 1] = excl + a0;
  if(2*t < dn){
    rowp[d0 + 2*t] = base + excl;
    if(DINV) dinv[d0 + 2*t] = a0 > 0 ? rsqrtf((float)a0) : 0.f;
  }
  if(2*t + 1 < dn){
    rowp[d0 + 2*t + 1] = base + excl + a0;
    if(DINV) dinv[d0 + 2*t + 1] = a1 > 0 ? rsqrtf((float)a1) : 0.f;
  }
  __syncthreads();

  for(int u = t; u < cnt; u += 256){
    int2 pr = ep[u];
    int pos = base + atomicAdd(&hcur[pr.x - d0], 1);
    col[pos] = pr.y;
    if(HAS_ATTR) attrp[pos] = battr[(size_t)b * cap + u];
  }
}

// ---------------------------------------------------------------- weights to bf16 frag-major

__global__ void cvt_weights(const float* __restrict__ Wl, const float* __restrict__ Wr,
                            const float* __restrict__ Wsrc, u16* __restrict__ Wb){
  const int total = 15 * H * H;
  for(int t = blockIdx.x*blockDim.x + threadIdx.x; t < total; t += gridDim.x*blockDim.x){
    int mat = t >> 14, idx = t & 16383;
    int k = idx >> 7, colj = idx & 127;
    const float* srcp = (mat < 7) ? (Wl + ((size_t)mat << 14))
                       : (mat < 14) ? (Wr + ((size_t)(mat - 7) << 14))
                       : Wsrc;
    Wb[((size_t)mat << 14) + (size_t)colj*H + k] = f2bf(srcp[idx]);
  }
}

__global__ void mat_vec_row(const float* __restrict__ W, const float* __restrict__ a,
                            float* __restrict__ outv){
  int k = threadIdx.x;
  if(k < H){
    float s = 0.f;
    for(int j = 0; j < H; j++) s += W[(size_t)k*H + j] * a[j];
    outv[k] = s;
  }
}

__global__ void dot128(const float* __restrict__ a, const float* __restrict__ b,
                       float* __restrict__ o){
  int l = threadIdx.x;
  float acc = a[l]*b[l] + a[l+64]*b[l+64];
  acc = waveReduceSum(acc);
  if(l == 0) o[0] = acc;
}

// ---------------------------------------------------------------- TAG (padded 8-float rows, dinv in slot 7)

template<int C>
__global__ void pack_rows(const float* __restrict__ x, const float* __restrict__ dinv,
                          float* __restrict__ xp, int N){
  for(int i = blockIdx.x*blockDim.x + threadIdx.x; i < N; i += gridDim.x*blockDim.x){
    #pragma unroll
    for(int k = 0; k < C; k++) xp[(size_t)i*8 + k] = x[(size_t)i*C + k];
    xp[(size_t)i*8 + 7] = dinv[i];
  }
}

template<int C>
__global__ void csr_tag_hop8(const int* __restrict__ rowp, const int* __restrict__ col,
                             const float* __restrict__ hin, float* __restrict__ hout, int N){
  for(int i = blockIdx.x*blockDim.x + threadIdx.x; i < N; i += gridDim.x*blockDim.x){
    int b = rowp[i], e = rowp[i+1];
    float dd = hin[(size_t)i*8 + 7];
    float acc0[C], acc1[C];
    #pragma unroll
    for(int k = 0; k < C; k++){ acc0[k] = 0.f; acc1[k] = 0.f; }
    int p = b;
    for(; p + 2 <= e; p += 2){
      const float* r0 = &hin[(size_t)col[p]   * 8];
      const float* r1 = &hin[(size_t)col[p+1] * 8];
      float w0 = r0[7] * dd, w1 = r1[7] * dd;
      #pragma unroll
      for(int k = 0; k < C; k++){
        acc0[k] += r0[k] * w0;
        acc1[k] += r1[k] * w1;
      }
    }
    if(p < e){
      const float* r0 = &hin[(size_t)col[p] * 8];
      float w0 = r0[7] * dd;
      #pragma unroll
      for(int k = 0; k < C; k++) acc0[k] += r0[k] * w0;
    }
    #pragma unroll
    for(int k = 0; k < C; k++) hout[(size_t)i*8 + k] = acc0[k] + acc1[k];
    hout[(size_t)i*8 + 7] = dd;
  }
}

template<int C>
__global__ __launch_bounds__(256) void tag_fuse(
    const float* __restrict__ x, const float* __restrict__ h1,
    const float* __restrict__ h2, const float* __restrict__ h3,
    const float* __restrict__ W, const float* __restrict__ bias,
    u16* __restrict__ out, int N){
  __shared__ float Ws[4*C*H];
  for(int u = threadIdx.x; u < 4*C*H; u += 256) Ws[u] = W[u];
  __syncthreads();
  const long long total = (long long)N * H;
  for(long long t = (long long)blockIdx.x*blockDim.x + threadIdx.x; t < total;
      t += (long long)gridDim.x*blockDim.x){
    int i = (int)(t >> 7), j = (int)(t & 127);
    const float* xr = x + (size_t)i*C;
    const float* r1 = h1 + (size_t)i*8;
    const float* r2 = h2 + (size_t)i*8;
    const float* r3 = h3 + (size_t)i*8;
    float acc = bias[j];
    #pragma unroll
    for(int k = 0; k < C; k++) acc += xr[k] * Ws[k*H + j];
    #pragma unroll
    for(int k = 0; k < C; k++) acc += r1[k] * Ws[(C + k)*H + j];
    #pragma unroll
    for(int k = 0; k < C; k++) acc += r2[k] * Ws[(2*C + k)*H + j];
    #pragma unroll
    for(int k = 0; k < C; k++) acc += r3[k] * Ws[(3*C + k)*H + j];
    out[t] = f2bf(fmaxf(acc, 0.f));
  }
}

// ---------------------------------------------------------------- SAGE gather (2 rows per wave)

// agg[i] = mean_{nbr} x[nbr].  Half-wave (32 lanes x 8B) per row -> 2 rows in
// flight per wave (2x MLP vs round-8's 1-row wave), 8-deep neighbor unroll.
__global__ void csr_gather2(const int* __restrict__ rowp, const int* __restrict__ col,
                            const u16* __restrict__ x, u16* __restrict__ agg, int N){
  int lane = threadIdx.x & 63;
  int half = lane >> 5;      // 0 / 1
  int hl   = lane & 31;      // 4 cols each (8B)
  long long w = (long long)((blockIdx.x*blockDim.x + threadIdx.x) >> 6);
  long long nw = (long long)((gridDim.x*blockDim.x) >> 6);
  for(long long i0 = w*2; i0 < N; i0 += nw*2){
    int i = (int)i0 + half;
    if(i < N){
      int b = rowp[i], e = rowp[i+1];
      float a0=0.f, a1=0.f, a2=0.f, a3=0.f;
      float b0=0.f, b1=0.f, b2=0.f, b3=0.f;
      int p = b;
      for(; p + 8 <= e; p += 8){
        uint2 v[8];
        #pragma unroll
        for(int j = 0; j < 8; j++)
          v[j] = *(const uint2*)&x[(size_t)col[p + j]*H + hl*4];
        #pragma unroll
        for(int j = 0; j < 4; j++){
          a0 += bflo(v[j].x); a1 += bfhi(v[j].x);
          a2 += bflo(v[j].y); a3 += bfhi(v[j].y);
          b0 += bflo(v[j+4].x); b1 += bfhi(v[j+4].x);
          b2 += bflo(v[j+4].y); b3 += bfhi(v[j+4].y);
        }
      }
      for(; p < e; p++){
        uint2 v = *(const uint2*)&x[(size_t)col[p]*H + hl*4];
        a0 += bflo(v.x); a1 += bfhi(v.x);
        a2 += bflo(v.y); a3 += bfhi(v.y);
      }
      float inv = 1.f / fmaxf((float)(e - b), 1.f);
      uint2 o;
      o.x = pack2((a0+b0)*inv, (a1+b1)*inv);
      o.y = pack2((a2+b2)*inv, (a3+b3)*inv);
      *(uint2*)&agg[(size_t)i*H + hl*4] = o;
    }
  }
}

// ---------------------------------------------------------------- MFMA combine (LDS-staged weights)

// out = maybe_relu( x@Wr [+ agg@Wl] [+ bl] ) bf16, f32 accumulate.
// Block: 4 waves x 32 rows = 128 rows. Weights staged once per block in LDS,
// XOR-swizzled (byte ^= (col&7)<<4) on both write and read (G4).
// In-place safe for out==x or out==agg: each block reads only its own rows
// into registers before any store.
template<bool HAS_AGG, bool RELU, bool BIAS>
__global__ __launch_bounds__(256) void combine_mfma(
    const u16* __restrict__ x, const u16* __restrict__ agg,
    const u16* __restrict__ WbR, const u16* __restrict__ WbL,
    const float* __restrict__ bl, u16* __restrict__ out, int N){
  __shared__ u16 Ws[(HAS_AGG ? 2 : 1) * H * H];

  #pragma unroll
  for(int m = 0; m < (HAS_AGG ? 2 : 1); m++){
    const u16* Wp = m ? WbL : WbR;
    char* dst = (char*)(Ws + m * H * H);
    for(int u = threadIdx.x; u < H * H / 8; u += 256){
      bf16x8 v = *(const bf16x8*)&Wp[u * 8];
      int c  = u >> 4;
      int kb = (u & 15) * 16;
      *(bf16x8*)(dst + c * 256 + (kb ^ ((c & 7) << 4))) = v;
    }
  }
  __syncthreads();

  const int lane = threadIdx.x & 63;
  const int wib  = threadIdx.x >> 6;
  const int m0   = (blockIdx.x * 4 + wib) * 32;
  if(m0 >= N) return;
  const int r16 = lane & 15;
  const int kg  = (lane >> 4) * 8;

  f32x4 acc[2][8];
  #pragma unroll
  for(int rt = 0; rt < 2; rt++)
    #pragma unroll
    for(int t = 0; t < 8; t++) acc[rt][t] = (f32x4){0.f, 0.f, 0.f, 0.f};

  #pragma unroll
  for(int phase = 0; phase < (HAS_AGG ? 2 : 1); phase++){
    const u16* Ap = phase ? agg : x;
    const char* Wbase = (const char*)(Ws + phase * H * H);
    #pragma unroll
    for(int k0 = 0; k0 < H; k0 += 32){
      bf16x8 af[2];
      #pragma unroll
      for(int rt = 0; rt < 2; rt++){
        int row = m0 + rt * 16 + r16;
        if(row < N) af[rt] = *(const bf16x8*)&Ap[(size_t)row * H + k0 + kg];
        else        af[rt] = (bf16x8){0,0,0,0,0,0,0,0};
      }
      #pragma unroll
      for(int t = 0; t < 8; t++){
        int c = t * 16 + r16;
        int kb = (k0 + kg) * 2;
        bf16x8 bf = *(const bf16x8*)(Wbase + c * 256 + (kb ^ ((c & 7) << 4)));
        acc[0][t] = __builtin_amdgcn_mfma_f32_16x16x32_bf16(af[0], bf, acc[0][t], 0, 0, 0);
        acc[1][t] = __builtin_amdgcn_mfma_f32_16x16x32_bf16(af[1], bf, acc[1][t], 0, 0, 0);
      }
    }
  }

  #pragma unroll
  for(int rt = 0; rt < 2; rt++){
    const int orow = m0 + rt * 16 + (lane >> 4) * 4;
    #pragma unroll
    for(int t = 0; t < 8; t++){
      int c = t * 16 + r16;
      float bb = BIAS ? bl[c] : 0.f;
      #pragma unroll
      for(int r = 0; r < 4; r++){
        if(orow + r < N){
          float v = acc[rt][t][r] + bb;
          if(RELU) v = fmaxf(v, 0.f);
          out[(size_t)(orow + r) * H + c] = f2bf(v);
        }
      }
    }
  }
}

// ---------------------------------------------------------------- GAT

__global__ void rowdot_bf(const u16* __restrict__ x, const float* __restrict__ v,
                          float* __restrict__ out, int N){
  int lane = threadIdx.x & 63;
  int w = (blockIdx.x*blockDim.x + threadIdx.x) >> 6;
  int nw = (gridDim.x*blockDim.x) >> 6;
  for(int i = w; i < N; i += nw){
    unsigned u = *(const unsigned*)&x[(size_t)i*H + lane*2];
    float acc = bflo(u)*v[lane*2] + bfhi(u)*v[lane*2 + 1];
    acc = waveReduceSum(acc);
    if(lane == 0) out[i] = acc;
  }
}

__global__ void gat_fused(const int* __restrict__ rowp, const int* __restrict__ colv,
                          const float* __restrict__ attrp, const float* __restrict__ av,
                          const float* __restrict__ ad, const float* __restrict__ cptr,
                          const u16* __restrict__ hs, const float* __restrict__ bias,
                          u16* __restrict__ out, int N){
  const float c = cptr[0];
  int lane = threadIdx.x & 63;
  int w = (blockIdx.x*blockDim.x + threadIdx.x) >> 6;
  int nw = (gridDim.x*blockDim.x) >> 6;
  for(int i = w; i < N; i += nw){
    int b = rowp[i], e = rowp[i+1];
    float adi = ad[i];
    float ax[4], ay[4];
    #pragma unroll
    for(int j = 0; j < 4; j++){ ax[j] = 0.f; ay[j] = 0.f; }
    float sume = 0.f;
    int p = b;
    for(; p + 4 <= e; p += 4){
      int s[4]; float lg[4]; unsigned v[4];
      #pragma unroll
      for(int j = 0; j < 4; j++) s[j] = colv[p + j];
      #pragma unroll
      for(int j = 0; j < 4; j++){
        float a = av[s[j]] + adi + attrp[p + j] * c;
        lg[j] = a > 0.f ? a : 0.2f * a;
        v[j] = *(const unsigned*)&hs[(size_t)s[j]*H + lane*2];
      }
      #pragma unroll
      for(int j = 0; j < 4; j++){
        float ee = __expf(lg[j]);
        ax[j] += ee * bflo(v[j]);
        ay[j] += ee * bfhi(v[j]);
        sume += ee;
      }
    }
    for(; p < e; p++){
      int s0 = colv[p];
      float a0 = av[s0] + adi + attrp[p] * c;
      a0 = a0 > 0.f ? a0 : 0.2f * a0;
      float e0 = __expf(a0);
      unsigned v0 = *(const unsigned*)&hs[(size_t)s0*H + lane*2];
      ax[0] += e0 * bflo(v0);
      ay[0] += e0 * bfhi(v0);
      sume += e0;
    }
    float rd = 1.f / fmaxf(sume, 1e-16f);
    float ox = fmaxf((ax[0]+ax[1]+ax[2]+ax[3]) * rd + bias[lane*2],     0.f);
    float oy = fmaxf((ay[0]+ay[1]+ay[2]+ay[3]) * rd + bias[lane*2 + 1], 0.f);
    *(unsigned*)&out[(size_t)i*H + lane*2] = pack2(ox, oy);
  }
}

// ---------------------------------------------------------------- single-matrix MFMA (hs = gx @ Wsrc)

__global__ __launch_bounds__(256) void gemm_mfma(
    const u16* __restrict__ x, const u16* __restrict__ Wb,
    u16* __restrict__ out, int N){
  __shared__ u16 Ws[H * H];
  const int t = threadIdx.x;
  for(int u = t; u < H*H/8; u += 256){
    bf16x8 v = *(const bf16x8*)&Wb[u*8];
    int c = u >> 4, kb = (u & 15) * 16;
    *(bf16x8*)((char*)Ws + c*256 + (kb ^ ((c & 7) << 4))) = v;
  }
  __syncthreads();

  const int lane = t & 63;
  const int wib = t >> 6;
  const int m0 = (blockIdx.x * 4 + wib) * 32;
  if(m0 >= N) return;
  const int r16 = lane & 15;
  const int kg = (lane >> 4) * 8;

  f32x4 acc[2][8];
  #pragma unroll
  for(int rt = 0; rt < 2; rt++)
    #pragma unroll
    for(int tt = 0; tt < 8; tt++) acc[rt][tt] = (f32x4){0.f,0.f,0.f,0.f};

  #pragma unroll
  for(int k0c = 0; k0c < 4; k0c++){
    int k0 = k0c * 32;
    bf16x8 af[2];
    #pragma unroll
    for(int rt = 0; rt < 2; rt++){
      int row = m0 + rt*16 + r16;
      if(row < N) af[rt] = *(const bf16x8*)&x[(size_t)row*H + k0 + kg];
      else        af[rt] = (bf16x8){0,0,0,0,0,0,0,0};
    }
    #pragma unroll
    for(int tt = 0; tt < 8; tt++){
      int c = tt*16 + r16;
      int kb = (k0 + kg)*2;
      bf16x8 bf = *(const bf16x8*)((char*)Ws + c*256 + (kb ^ ((c & 7) << 4)));
      acc[0][tt] = __builtin_amdgcn_mfma_f32_16x16x32_bf16(af[0], bf, acc[0][tt], 0, 0, 0);
      acc[1][tt] = __builtin_amdgcn_mfma_f32_16x16x32_bf16(af[1], bf, acc[1][tt], 0, 0, 0);
    }
  }

  #pragma unroll
  for(int rt = 0; rt < 2; rt++){
    const int orow = m0 + rt*16 + (lane >> 4) * 4;
    #pragma unroll
    for(int tt = 0; tt < 8; tt++){
      int c = tt*16 + r16;
      #pragma unroll
      for(int r = 0; r < 4; r++){
        if(orow + r < N)
          out[(size_t)(orow + r)*H + c] = f2bf(acc[rt][tt][r]);
      }
    }
  }
}

__global__ void mlp_out_bf(const u16* __restrict__ x, const float* __restrict__ W,
                           const float* __restrict__ b, float* __restrict__ out, int N){
  int lane = threadIdx.x & 63;
  int w = (blockIdx.x*blockDim.x + threadIdx.x) >> 6;
  int nw = (gridDim.x*blockDim.x) >> 6;
  for(int i = w; i < N; i += nw){
    unsigned u = *(const unsigned*)&x[(size_t)i*H + lane*2];
    float acc = bflo(u)*W[lane*2] + bfhi(u)*W[lane*2 + 1];
    acc = waveReduceSum(acc);
    if(lane == 0) out[i] = acc + b[0];
  }
}

// ---------------------------------------------------------------- launch

extern "C" void kernel_launch(void* const* d_in, const int* in_sizes, int n_in,
                              void* d_out, int out_size, void* d_ws, size_t ws_size,
                              hipStream_t stream) {
  const float* game_x  = (const float*)d_in[0];
  const float* state_x = (const float*)d_in[1];
  const int*   e_vv    = (const int*)d_in[2];
  const int*   e_hist  = (const int*)d_in[4];
  const float* attr_h  = (const float*)d_in[5];
  const int*   e_in    = (const int*)d_in[6];
  const int*   e_ss    = (const int*)d_in[7];
  const float* tag1_W  = (const float*)d_in[8];
  const float* tag1_b  = (const float*)d_in[9];
  const float* tag2_W  = (const float*)d_in[10];
  const float* tag2_b  = (const float*)d_in[11];
  const float* sage_Wl = (const float*)d_in[12];
  const float* sage_bl = (const float*)d_in[13];
  const float* sage_Wr = (const float*)d_in[14];
  const float* gat_Wsrc= (const float*)d_in[15];
  const float* gat_Wdst= (const float*)d_in[16];
  const float* gat_We  = (const float*)d_in[17];
  const float* gat_asrc= (const float*)d_in[18];
  const float* gat_adst= (const float*)d_in[19];
  const float* gat_ae  = (const float*)d_in[20];
  const float* gat_b   = (const float*)d_in[21];
  const float* mlp_W   = (const float*)d_in[22];
  const float* mlp_b   = (const float*)d_in[23];
  float* out = (float*)d_out;

  const int NV  = in_sizes[0] / 5;
  const int NS  = in_sizes[1] / 6;
  const int EVV = in_sizes[2] / 2;
  const int EH  = in_sizes[4] / 2;
  const int EIN = in_sizes[6] / 2;
  const int ESS = in_sizes[7] / 2;

  const int* vv_src = e_vv;   const int* vv_dst = e_vv + EVV;
  const int* eh_src = e_hist; const int* eh_dst = e_hist + EH;
  const int* in_src = e_in;   const int* in_dst = e_in + EIN;
  const int* ss_src = e_ss;   const int* ss_dst = e_ss + ESS;

  const int NBv = (NV + 511) >> BSHIFT;
  const int NBs = (NS + 511) >> BSHIFT;
  const int capvv = (EVV / NBv) * 3 / 2 + 64;
  const int capss = (ESS / NBs) * 3 / 2 + 64;
  const int capeh = (EH  / NBs) * 3 / 2 + 64;
  const int capin = (EIN / NBs) * 3 / 2 + 64;

  char* wp = (char*)d_ws;
  auto alloc = [&](size_t bytes) -> void* {
    void* p = (void*)wp;
    wp += (bytes + 511) & ~size_t(511);
    return p;
  };
  u16* V0 = (u16*)alloc((size_t)NV*H*2);
  u16* V1 = (u16*)alloc((size_t)NV*H*2);
  u16* S0 = (u16*)alloc((size_t)NS*H*2);
  u16* S1 = (u16*)alloc((size_t)NS*H*2);
  u16* Wb = (u16*)alloc((size_t)15*H*H*2);
  float* dinv_v = (float*)alloc((size_t)NV*4);
  float* dinv_s = (float*)alloc((size_t)NS*4);
  float* av   = (float*)alloc((size_t)NV*4);
  float* ad   = (float*)alloc((size_t)NS*4);
  float* xp5  = (float*)alloc((size_t)NV*8*4);
  float* h5a  = (float*)alloc((size_t)NV*8*4);
  float* h5b  = (float*)alloc((size_t)NV*8*4);
  float* h5c  = (float*)alloc((size_t)NV*8*4);
  float* xp6  = (float*)alloc((size_t)NS*8*4);
  float* h6a  = (float*)alloc((size_t)NS*8*4);
  float* h6b  = (float*)alloc((size_t)NS*8*4);
  float* h6c  = (float*)alloc((size_t)NS*8*4);
  float* wvec = (float*)alloc(H*4);
  float* cbuf = (float*)alloc(4);
  int* vv_rowp = (int*)alloc((size_t)(NV+1)*4);
  int* vv_col  = (int*)alloc((size_t)EVV*4);
  int* ss_rowp = (int*)alloc((size_t)(NS+1)*4);
  int* ss_col  = (int*)alloc((size_t)ESS*4);
  int* eh_rowp = (int*)alloc((size_t)(NS+1)*4);
  int* eh_col  = (int*)alloc((size_t)EH*4);
  float* eh_attr = (float*)alloc((size_t)EH*4);
  int* in_rowp = (int*)alloc((size_t)(NS+1)*4);
  int* in_col  = (int*)alloc((size_t)EIN*4);
  int2* vv_bp = (int2*)alloc((size_t)NBv*capvv*8);
  int2* ss_bp = (int2*)alloc((size_t)NBs*capss*8);
  int2* eh_bp = (int2*)alloc((size_t)NBs*capeh*8);
  int2* in_bp = (int2*)alloc((size_t)NBs*capin*8);
  float* eh_ba = (float*)alloc((size_t)NBs*capeh*4);
  int* bcur  = (int*)alloc(4*256*4);
  int* bbase = (int*)alloc(4*256*4);
  (void)ws_size; (void)n_in; (void)out_size;

  const int B = 256;
  #define GRID1(n) gridFor((long long)(n), B, 8192), B, 0, stream
  #define GRIDW(e) gridFor((long long)(e) * 64, B, 16384), B, 0, stream
  #define GRIDW2(e) gridFor((long long)(e) * 32, B, 16384), B, 0, stream
  #define GEMM(n)  ((n) + 127) / 128, 256, 0, stream

  // ---- bucketed CSR build
  hipMemsetAsync(bcur, 0, 4*256*4, stream);
  part_kernel<false><<<(EVV + CH - 1)/CH, 256, 0, stream>>>(
      vv_src, vv_dst, nullptr, bcur + 0,   vv_bp, nullptr, EVV, capvv);
  part_kernel<false><<<(ESS + CH - 1)/CH, 256, 0, stream>>>(
      ss_src, ss_dst, nullptr, bcur + 256, ss_bp, nullptr, ESS, capss);
  part_kernel<true ><<<(EH  + CH - 1)/CH, 256, 0, stream>>>(
      eh_src, eh_dst, attr_h,  bcur + 512, eh_bp, eh_ba,   EH,  capeh);
  part_kernel<false><<<(EIN + CH - 1)/CH, 256, 0, stream>>>(
      in_src, in_dst, nullptr, bcur + 768, in_bp, nullptr, EIN, capin);
  bucket_scan<<<4, 256, 0, stream>>>(bcur, bbase, vv_rowp, ss_rowp, eh_rowp, in_rowp,
                                     NV, NS, NS, NS);
  build_kernel<false,true ><<<NBv, 256, 0, stream>>>(
      vv_bp, nullptr, bcur + 0,   bbase + 0,   vv_rowp, vv_col, nullptr, dinv_v, capvv, NV);
  build_kernel<false,true ><<<NBs, 256, 0, stream>>>(
      ss_bp, nullptr, bcur + 256, bbase + 256, ss_rowp, ss_col, nullptr, dinv_s, capss, NS);
  build_kernel<true ,false><<<NBs, 256, 0, stream>>>(
      eh_bp, eh_ba,   bcur + 512, bbase + 512, eh_rowp, eh_col, eh_attr, nullptr, capeh, NS);
  build_kernel<false,false><<<NBs, 256, 0, stream>>>(
      in_bp, nullptr, bcur + 768, bbase + 768, in_rowp, in_col, nullptr, nullptr, capin, NS);

  // ---- weight prep
  cvt_weights<<<GRID1(15*H*H)>>>(sage_Wl, sage_Wr, gat_Wsrc, Wb);
  mat_vec_row<<<1, 128, 0, stream>>>(gat_Wdst, gat_adst, wvec);
  dot128<<<1, 64, 0, stream>>>(gat_We, gat_ae, cbuf);

  #define WBL(l) (Wb + ((size_t)(l) << 14))
  #define WBR(l) (Wb + ((size_t)(7 + (l)) << 14))

  // ---- TAG1 (game tower) -> V0
  pack_rows<5><<<GRID1(NV)>>>(game_x, dinv_v, xp5, NV);
  csr_tag_hop8<5><<<GRID1(NV)>>>(vv_rowp, vv_col, xp5, h5a, NV);
  csr_tag_hop8<5><<<GRID1(NV)>>>(vv_rowp, vv_col, h5a, h5b, NV);
  csr_tag_hop8<5><<<GRID1(NV)>>>(vv_rowp, vv_col, h5b, h5c, NV);
  tag_fuse<5><<<GRID1((long long)NV*H)>>>(game_x, h5a, h5b, h5c, tag1_W, tag1_b, V0, NV);

  // ---- SAGE 0,1 on vv (gather -> V1, combine in-place on V0)
  csr_gather2<<<GRIDW2(NV)>>>(vv_rowp, vv_col, V0, V1, NV);
  combine_mfma<true,true,true><<<GEMM(NV)>>>(V0, V1, WBR(0), WBL(0),
                                             sage_bl + 0*H, V0, NV);
  csr_gather2<<<GRIDW2(NV)>>>(vv_rowp, vv_col, V0, V1, NV);
  combine_mfma<true,true,true><<<GEMM(NV)>>>(V0, V1, WBR(1), WBL(1),
                                             sage_bl + 1*H, V0, NV);   // gx = V0

  // ---- TAG2 (state tower) -> S0
  pack_rows<6><<<GRID1(NS)>>>(state_x, dinv_s, xp6, NS);
  csr_tag_hop8<6><<<GRID1(NS)>>>(ss_rowp, ss_col, xp6, h6a, NS);
  csr_tag_hop8<6><<<GRID1(NS)>>>(ss_rowp, ss_col, h6a, h6b, NS);
  csr_tag_hop8<6><<<GRID1(NS)>>>(ss_rowp, ss_col, h6b, h6c, NS);
  tag_fuse<6><<<GRID1((long long)NS*H)>>>(state_x, h6a, h6b, h6c, tag2_W, tag2_b, S0, NS);

  // ---- SAGE 2,3 on ss (combine in-place on S0)
  csr_gather2<<<GRIDW2(NS)>>>(ss_rowp, ss_col, S0, S1, NS);
  combine_mfma<true,true,true><<<GEMM(NS)>>>(S0, S1, WBR(2), WBL(2),
                                             sage_bl + 2*H, S0, NS);
  csr_gather2<<<GRIDW2(NS)>>>(ss_rowp, ss_col, S0, S1, NS);
  combine_mfma<true,true,true><<<GEMM(NS)>>>(S0, S1, WBR(3), WBL(3),
                                             sage_bl + 3*H, S0, NS);   // sx = S0

  // ---- GAT (gx -> sx) : hist -> S1
  gemm_mfma<<<GEMM(NV)>>>(V0, Wb + ((size_t)14 << 14), V1, NV);        // hs -> V1
  rowdot_bf<<<GRIDW(NV)>>>(V1, gat_asrc, av, NV);
  rowdot_bf<<<GRIDW(NS)>>>(S0, wvec, ad, NS);                          // ad = sx @ (Wdst@adst)
  gat_fused<<<GRIDW(NS)>>>(eh_rowp, eh_col, eh_attr, av, ad, cbuf, V1, gat_b, S1, NS);

  // ---- SAGE4: gather gx over in-CSR -> S0; combine(x=hist(S1), agg=S0) -> S1
  csr_gather2<<<GRIDW2(NS)>>>(in_rowp, in_col, V0, S0, NS);
  combine_mfma<true,true,true><<<GEMM(NS)>>>(S1, S0, WBR(4), WBL(4),
                                             sage_bl + 4*H, S1, NS);

  // ---- SAGE 5,6 on ss (combine in-place on S1)
  csr_gather2<<<GRIDW2(NS)>>>(ss_rowp, ss_col, S1, S0, NS);
  combine_mfma<true,true,true><<<GEMM(NS)>>>(S1, S0, WBR(5), WBL(5),
                                             sage_bl + 5*H, S1, NS);
  csr_gather2<<<GRIDW2(NS)>>>(ss_rowp, ss_col, S1, S0, NS);
  combine_mfma<true,true,true><<<GEMM(NS)>>>(S1, S0, WBR(6), WBL(6),
                                             sage_bl + 6*H, S1, NS);

  // ---- final MLP -> d_out (f32)
  mlp_out_bf<<<GRIDW(NS)>>>(S1, mlp_W, mlp_b, out, NS);

  #undef GRID1
  #undef GRIDW
  #undef GRIDW2
  #undef GEMM
  #undef WBL
  #undef WBR
}